// Round 3
// baseline (389.402 us; speedup 1.0000x reference)
//
#include <hip/hip_runtime.h>
#include <hip/hip_bf16.h>

// Problem constants (B=2, T=2048, C=1024, NH=16, NKV=8, HD=64, Q_PER_KV=2)
#define BB 2
#define TT 2048
#define CC 1024
#define NH 16
#define NKV 8
#define HD 64

typedef __attribute__((ext_vector_type(8))) short short8;   // 8 bf16 (MFMA A/B frag)
typedef __attribute__((ext_vector_type(4))) float float4v;  // MFMA C/D frag

__device__ __forceinline__ ushort f2bf(float f) {
    __hip_bfloat16 h = __float2bfloat16(f);
    union { __hip_bfloat16 h; ushort u; } v; v.h = h; return v.u;
}

// ---------------------------------------------------------------------------
// f32 -> bf16 convert (n multiple of 4)
// ---------------------------------------------------------------------------
__global__ __launch_bounds__(256) void conv_kernel(
    const float* __restrict__ src, ushort* __restrict__ dst, int n)
{
    int i = (blockIdx.x * 256 + threadIdx.x) * 4;
    if (i + 3 < n) {
        float4 v = *(const float4*)&src[i];
        dst[i + 0] = f2bf(v.x);
        dst[i + 1] = f2bf(v.y);
        dst[i + 2] = f2bf(v.z);
        dst[i + 3] = f2bf(v.w);
    }
}

// Pack Wq(1024x1024)|Wk(1024x512)|Wv(1024x512) -> bf16 [1024][2048]
__global__ __launch_bounds__(256) void pack_qkv_w_kernel(
    const float* __restrict__ Wq, const float* __restrict__ Wk,
    const float* __restrict__ Wv, ushort* __restrict__ dst)
{
    int idx = blockIdx.x * 256 + threadIdx.x;   // over 1024*2048
    int k = idx >> 11, n = idx & 2047;
    float v;
    if (n < 1024)      v = Wq[k * 1024 + n];
    else if (n < 1536) v = Wk[k * 512 + (n - 1024)];
    else               v = Wv[k * 512 + (n - 1536)];
    dst[idx] = f2bf(v);
}

// ---------------------------------------------------------------------------
// bf16 GEMM: C(MxN) = A(MxK) @ B(KxN); A,B row-major bf16; C f32.
// Tile BMx128, BK=32, 4 waves. BM=128 -> 64x64/wave; BM=64 -> 32x64/wave.
// ---------------------------------------------------------------------------
template<int BM>
__global__ __launch_bounds__(256) void gemm_kernel(
    const ushort* __restrict__ A, const ushort* __restrict__ Bm,
    float* __restrict__ Cp, int M, int N, int K, int ldc)
{
    constexpr int RT = BM / 32;
    __shared__ ushort As[BM][40];    // [m][k], +8 pad
    __shared__ ushort Bs[128][40];   // [n][k] (transposed), +8 pad

    const int m0 = blockIdx.x * BM;
    const int n0 = blockIdx.y * 128;
    const int tid = threadIdx.x;
    const int lane = tid & 63;
    const int w = tid >> 6;
    const int wm = (w >> 1) * (BM / 2), wn = (w & 1) * 64;

    float4v acc[RT][4] = {};

    for (int k0 = 0; k0 < K; k0 += 32) {
        #pragma unroll
        for (int i = 0; i < BM / 64; i++) {
            int idx = tid + i * 256;
            int r = idx >> 2, q = idx & 3;
            uint4 v = *(const uint4*)&A[(size_t)(m0 + r) * K + k0 + q * 8];
            *(uint4*)&As[r][q * 8] = v;
        }
        #pragma unroll
        for (int i = 0; i < 2; i++) {
            int idx = tid + i * 256;
            int kr = idx >> 4, nc = (idx & 15) * 8;
            ushort tmp[8];
            *(uint4*)tmp = *(const uint4*)&Bm[(size_t)(k0 + kr) * N + n0 + nc];
            #pragma unroll
            for (int j = 0; j < 8; j++) Bs[nc + j][kr] = tmp[j];
        }
        __syncthreads();

        short8 af[RT], bf[4];
        #pragma unroll
        for (int t = 0; t < RT; t++)
            af[t] = *(const short8*)&As[wm + t * 16 + (lane & 15)][(lane >> 4) * 8];
        #pragma unroll
        for (int t = 0; t < 4; t++)
            bf[t] = *(const short8*)&Bs[wn + t * 16 + (lane & 15)][(lane >> 4) * 8];
        #pragma unroll
        for (int rt = 0; rt < RT; rt++)
            #pragma unroll
            for (int ct = 0; ct < 4; ct++)
                acc[rt][ct] = __builtin_amdgcn_mfma_f32_16x16x32_bf16(af[rt], bf[ct], acc[rt][ct], 0, 0, 0);
        __syncthreads();
    }

    // D layout: col=lane&15, row=(lane>>4)*4+r  [m89/m91 verified]
    #pragma unroll
    for (int rt = 0; rt < RT; rt++)
        #pragma unroll
        for (int ct = 0; ct < 4; ct++)
            #pragma unroll
            for (int r = 0; r < 4; r++) {
                int row = m0 + wm + rt * 16 + (lane >> 4) * 4 + r;
                int col = n0 + wn + ct * 16 + (lane & 15);
                Cp[(size_t)row * ldc + col] = acc[rt][ct][r];
            }
}

// ---------------------------------------------------------------------------
// Per-(b,t): gate + ve-add, RoPE + RMSNorm. qkv row = [q(1024)|k(512)|v(512)] f32.
// Writes Q (B,NH,T,HD), K (B,NKV,T,HD), V TRANSPOSED (B,NKV,HD,T) in bf16.
// ---------------------------------------------------------------------------
__global__ __launch_bounds__(256) void qkv_post_kernel(
    const float* __restrict__ qkv, const float* __restrict__ x,
    const float* __restrict__ ve, const float* __restrict__ cosb,
    const float* __restrict__ sinb, const float* __restrict__ wgate,
    ushort* __restrict__ Qb, ushort* __restrict__ Kb, ushort* __restrict__ Vt)
{
    const int bt = blockIdx.x;
    const int b = bt >> 11, t = bt & 2047;
    const int tid = threadIdx.x;
    const int lane = tid & 63;
    const int w = tid >> 6;
    __shared__ float gateS[8];

    // gate[g] = 2*sigmoid(x[bt,:32] @ Wgate[:,g]); 32 threads per g
    {
        int g = tid >> 5, i = tid & 31;
        float p = x[(size_t)bt * CC + i] * wgate[i * 8 + g];
        #pragma unroll
        for (int off = 16; off; off >>= 1) p += __shfl_down(p, off, 32);
        if (i == 0) gateS[g] = 2.f / (1.f + __expf(-p));
    }
    __syncthreads();

    // RoPE + RMSNorm: heads 0..15 = q, 16..23 = k
    const float c = cosb[t * 32 + (lane & 31)];
    const float s = sinb[t * 32 + (lane & 31)];
    for (int hh = w; hh < 24; hh += 4) {
        const float* z = &qkv[(size_t)bt * 2048 + hh * 64];
        float v = z[lane];
        float other = __shfl_xor(v, 32);
        float x1 = (lane < 32) ? v : other;
        float x2 = (lane < 32) ? other : v;
        float val = (lane < 32) ? (x1 * c + x2 * s) : (-x1 * s + x2 * c);
        float ss = val * val;
        #pragma unroll
        for (int off = 32; off; off >>= 1) ss += __shfl_xor(ss, off);
        float scale = rsqrtf(ss * (1.f / 64.f) + 1.1920929e-07f);
        ushort ob = f2bf(val * scale);
        if (hh < 16) Qb[(((size_t)b * NH + hh) * TT + t) * HD + lane] = ob;
        else         Kb[(((size_t)b * NKV + (hh - 16)) * TT + t) * HD + lane] = ob;
    }

    // v = v + gate*ve; store transposed (B,NKV,HD,T)
    for (int e = tid; e < NKV * HD; e += 256) {
        int kh = e >> 6, d = e & 63;
        float v = qkv[(size_t)bt * 2048 + 1536 + e] + gateS[kh] * ve[(size_t)bt * 512 + e];
        Vt[(((size_t)b * NKV + kh) * HD + d) * TT + t] = f2bf(v);
    }
}

// ---------------------------------------------------------------------------
// Barrier-free flash attention: 1 wave per block, 32 q-rows per wave.
// K/V frags loaded directly from global (L2/L3-resident); V pre-transposed.
// Wave-private LDS only for P C->A layout round-trip. Grid: heavy-first.
// ---------------------------------------------------------------------------
__global__ __launch_bounds__(64) void attn_kernel(
    const ushort* __restrict__ Qb, const ushort* __restrict__ Kb,
    const ushort* __restrict__ Vt, ushort* __restrict__ Yb,
    const int* __restrict__ winp)
{
    // heavy-first mapping: global heads (desc q), then local heads (desc q)
    const int gid = blockIdx.x;
    int b, h, qw;
    if (gid < 1024) { qw = 63 - (gid >> 4); h = (gid >> 1) & 7; b = gid & 1; }
    else { int j = gid - 1024; qw = 63 - (j >> 4); h = 8 + ((j >> 1) & 7); b = j & 1; }

    const int q0 = qw * 32;
    const int kvh = h >> 1;
    const bool local = (h >= 8);
    int window = *winp;
    if (window < 0 || window > TT) window = TT;
    const int lane = threadIdx.x;
    const int lr = lane & 15, lc = lane >> 4;

    __shared__ ushort Ps[16][72];   // wave-private P scratch (C->A layout)

    const ushort* qbase = &Qb[(((size_t)b * NH + h) * TT + q0) * HD];
    short8 qf[2][2];
    #pragma unroll
    for (int rt = 0; rt < 2; rt++)
        #pragma unroll
        for (int x = 0; x < 2; x++)
            qf[rt][x] = *(const short8*)&qbase[(size_t)(rt * 16 + lr) * HD + x * 32 + lc * 8];

    float4v o[2][4] = {};
    float m_[2][4], l_[2][4];
    #pragma unroll
    for (int rt = 0; rt < 2; rt++)
        #pragma unroll
        for (int r = 0; r < 4; r++) { m_[rt][r] = -1e30f; l_[rt][r] = 0.f; }

    const ushort* Kbase = &Kb[((size_t)b * NKV + kvh) * TT * HD];
    const ushort* Vbase = &Vt[((size_t)b * NKV + kvh) * HD * TT];

    const int qlast = q0 + 31;
    int jstart = 0;
    if (local) { int js = q0 - window; if (js > 0) jstart = js & ~63; }

    for (int j0 = jstart; j0 <= qlast; j0 += 64) {
        // V B-frags: vf[ct][half], contiguous in t from transposed layout
        short8 vf[4][2];
        #pragma unroll
        for (int ct = 0; ct < 4; ct++) {
            const ushort* vp = &Vbase[(size_t)(ct * 16 + lr) * TT + j0 + lc * 8];
            vf[ct][0] = *(const short8*)vp;
            vf[ct][1] = *(const short8*)(vp + 32);
        }

        // S = Q @ K^T
        float4v sv[2][4];
        #pragma unroll
        for (int jt = 0; jt < 4; jt++) {
            const ushort* kp = &Kbase[(size_t)(j0 + jt * 16 + lr) * HD + lc * 8];
            short8 kf0 = *(const short8*)kp;
            short8 kf1 = *(const short8*)(kp + 32);
            #pragma unroll
            for (int rt = 0; rt < 2; rt++) {
                float4v z = {};
                z = __builtin_amdgcn_mfma_f32_16x16x32_bf16(qf[rt][0], kf0, z, 0, 0, 0);
                z = __builtin_amdgcn_mfma_f32_16x16x32_bf16(qf[rt][1], kf1, z, 0, 0, 0);
                sv[rt][jt] = z;
            }
        }

        #pragma unroll
        for (int rt = 0; rt < 2; rt++) {
            const int rowb = q0 + rt * 16 + lc * 4;
            // scale + mask (D layout: row=lc*4+r, col=lr)
            #pragma unroll
            for (int jt = 0; jt < 4; jt++) {
                int col = j0 + jt * 16 + lr;
                #pragma unroll
                for (int r = 0; r < 4; r++) {
                    int row = rowb + r;
                    float v = sv[rt][jt][r] * 0.125f;
                    bool ok = (col <= row) && (!local || col >= row - window);
                    sv[rt][jt][r] = ok ? v : -1e30f;
                }
            }
            // online softmax (rows in 16-lane groups)
            float pf[4][4];
            #pragma unroll
            for (int r = 0; r < 4; r++) {
                float mx = fmaxf(fmaxf(sv[rt][0][r], sv[rt][1][r]), fmaxf(sv[rt][2][r], sv[rt][3][r]));
                #pragma unroll
                for (int off = 1; off < 16; off <<= 1) mx = fmaxf(mx, __shfl_xor(mx, off));
                float mnew = fmaxf(m_[rt][r], mx);
                float alpha = __expf(fminf(m_[rt][r] - mnew, 0.f));
                m_[rt][r] = mnew;
                float ps = 0.f;
                #pragma unroll
                for (int jt = 0; jt < 4; jt++) {
                    float sval = sv[rt][jt][r];
                    float p = (sval > -1e29f) ? __expf(fminf(sval - mnew, 0.f)) : 0.f;
                    pf[jt][r] = p;
                    ps += p;
                }
                #pragma unroll
                for (int off = 1; off < 16; off <<= 1) ps += __shfl_xor(ps, off);
                l_[rt][r] = l_[rt][r] * alpha + ps;
                #pragma unroll
                for (int ct = 0; ct < 4; ct++) o[rt][ct][r] *= alpha;
            }
            // P: C-layout -> LDS -> A-layout (same-wave, no barrier needed)
            #pragma unroll
            for (int jt = 0; jt < 4; jt++)
                #pragma unroll
                for (int r = 0; r < 4; r++)
                    Ps[lc * 4 + r][jt * 16 + lr] = f2bf(pf[jt][r]);
            short8 pf0 = *(const short8*)&Ps[lr][lc * 8];
            short8 pf1 = *(const short8*)&Ps[lr][32 + lc * 8];
            #pragma unroll
            for (int ct = 0; ct < 4; ct++) {
                o[rt][ct] = __builtin_amdgcn_mfma_f32_16x16x32_bf16(pf0, vf[ct][0], o[rt][ct], 0, 0, 0);
                o[rt][ct] = __builtin_amdgcn_mfma_f32_16x16x32_bf16(pf1, vf[ct][1], o[rt][ct], 0, 0, 0);
            }
        }
    }

    // normalize + write y (B,T,NH*HD) bf16
    #pragma unroll
    for (int rt = 0; rt < 2; rt++)
        #pragma unroll
        for (int ct = 0; ct < 4; ct++)
            #pragma unroll
            for (int r = 0; r < 4; r++) {
                int trow = q0 + rt * 16 + lc * 4 + r;
                int col = h * HD + ct * 16 + lr;
                float denom = fmaxf(l_[rt][r], 1e-20f);
                Yb[((size_t)b * TT + trow) * CC + col] = f2bf(o[rt][ct][r] / denom);
            }
}

// ---------------------------------------------------------------------------
extern "C" void kernel_launch(void* const* d_in, const int* in_sizes, int n_in,
                              void* d_out, int out_size, void* d_ws, size_t ws_size,
                              hipStream_t stream) {
    (void)in_sizes; (void)n_in; (void)out_size; (void)ws_size;
    const float* x     = (const float*)d_in[0];
    const float* ve    = (const float*)d_in[1];
    const float* cosb  = (const float*)d_in[2];
    const float* sinb  = (const float*)d_in[3];
    const float* Wq    = (const float*)d_in[4];
    const float* Wk    = (const float*)d_in[5];
    const float* Wv    = (const float*)d_in[6];
    const float* Wproj = (const float*)d_in[7];
    const float* Wgate = (const float*)d_in[8];
    const int*   winp  = (const int*)d_in[9];
    float* out = (float*)d_out;

    char* ws = (char*)d_ws;
    float*  qkv  = (float*)ws;                      // 32 MiB (dead after qkv_post)
    ushort* Yb   = (ushort*)ws;                     // 8 MiB, overlays qkv
    ushort* xb   = (ushort*)(ws + 33554432);        // 8 MiB
    ushort* Wqkvb= (ushort*)(ws + 41943040);        // 4 MiB
    ushort* Wpb  = (ushort*)(ws + 46137344);        // 2 MiB
    ushort* Qb   = (ushort*)(ws + 48234496);        // 8 MiB
    ushort* Kb   = (ushort*)(ws + 56623104);        // 4 MiB
    ushort* Vtb  = (ushort*)(ws + 60817408);        // 4 MiB (B,NKV,HD,T)

    dim3 blk(256);
    // one-shot conversions
    conv_kernel<<<dim3(4096), blk, 0, stream>>>(x, xb, BB * TT * CC);
    pack_qkv_w_kernel<<<dim3(8192), blk, 0, stream>>>(Wq, Wk, Wv, Wqkvb);
    conv_kernel<<<dim3(1024), blk, 0, stream>>>(Wproj, Wpb, CC * CC);
    // fused QKV projection (f32 out, row = [q|k|v])
    gemm_kernel<128><<<dim3(32, 16), blk, 0, stream>>>(xb, Wqkvb, qkv, 4096, 2048, 1024, 2048);
    // gate/ve/rope/rmsnorm (+ V transpose)
    qkv_post_kernel<<<dim3(BB * TT), blk, 0, stream>>>(qkv, x, ve, cosb, sinb, Wgate, Qb, Kb, Vtb);
    // attention: 2048 single-wave blocks, heavy-first
    attn_kernel<<<dim3(2048), dim3(64), 0, stream>>>(Qb, Kb, Vtb, Yb, winp);
    // output projection -> f32 d_out (64-row tiles: 512 blocks, 2/CU)
    gemm_kernel<64><<<dim3(64, 8), blk, 0, stream>>>(Yb, Wpb, out, 4096, 1024, 1024, 1024);
}

// Round 4
// 332.798 us; speedup vs baseline: 1.1701x; 1.1701x over previous
//
#include <hip/hip_runtime.h>
#include <hip/hip_bf16.h>

// Problem constants (B=2, T=2048, C=1024, NH=16, NKV=8, HD=64, Q_PER_KV=2)
#define BB 2
#define TT 2048
#define CC 1024
#define NH 16
#define NKV 8
#define HD 64

typedef __attribute__((ext_vector_type(8))) short short8;   // 8 bf16 (MFMA A/B frag)
typedef __attribute__((ext_vector_type(4))) float float4v;  // MFMA C/D frag

__device__ __forceinline__ ushort f2bf(float f) {
    __hip_bfloat16 h = __float2bfloat16(f);
    union { __hip_bfloat16 h; ushort u; } v; v.h = h; return v.u;
}

// ---------------------------------------------------------------------------
// f32 -> bf16 convert (n multiple of 4)
// ---------------------------------------------------------------------------
__global__ __launch_bounds__(256) void conv_kernel(
    const float* __restrict__ src, ushort* __restrict__ dst, int n)
{
    int i = (blockIdx.x * 256 + threadIdx.x) * 4;
    if (i + 3 < n) {
        float4 v = *(const float4*)&src[i];
        dst[i + 0] = f2bf(v.x);
        dst[i + 1] = f2bf(v.y);
        dst[i + 2] = f2bf(v.z);
        dst[i + 3] = f2bf(v.w);
    }
}

// Pack Wq(1024x1024)|Wk(1024x512)|Wv(1024x512) -> bf16 [1024][2048]
__global__ __launch_bounds__(256) void pack_qkv_w_kernel(
    const float* __restrict__ Wq, const float* __restrict__ Wk,
    const float* __restrict__ Wv, ushort* __restrict__ dst)
{
    int idx = blockIdx.x * 256 + threadIdx.x;   // over 1024*2048
    int k = idx >> 11, n = idx & 2047;
    float v;
    if (n < 1024)      v = Wq[k * 1024 + n];
    else if (n < 1536) v = Wk[k * 512 + (n - 1024)];
    else               v = Wv[k * 512 + (n - 1536)];
    dst[idx] = f2bf(v);
}

// ---------------------------------------------------------------------------
// bf16 GEMM: C(MxN) = A(MxK) @ B(KxN); A,B row-major bf16; C f32.
// Tile 128x128, BK=32, 4 waves (each 64x64).
// ---------------------------------------------------------------------------
__global__ __launch_bounds__(256) void gemm_kernel(
    const ushort* __restrict__ A, const ushort* __restrict__ Bm,
    float* __restrict__ Cp, int M, int N, int K, int ldc)
{
    __shared__ ushort As[128][40];   // [m][k], +8 pad
    __shared__ ushort Bs[128][40];   // [n][k] (transposed), +8 pad

    const int m0 = blockIdx.x * 128;
    const int n0 = blockIdx.y * 128;
    const int tid = threadIdx.x;
    const int lane = tid & 63;
    const int w = tid >> 6;
    const int wm = (w >> 1) * 64, wn = (w & 1) * 64;

    float4v acc[4][4] = {};

    for (int k0 = 0; k0 < K; k0 += 32) {
        #pragma unroll
        for (int i = 0; i < 2; i++) {
            int idx = tid + i * 256;
            int r = idx >> 2, q = idx & 3;
            uint4 v = *(const uint4*)&A[(size_t)(m0 + r) * K + k0 + q * 8];
            *(uint4*)&As[r][q * 8] = v;
        }
        #pragma unroll
        for (int i = 0; i < 2; i++) {
            int idx = tid + i * 256;
            int kr = idx >> 4, nc = (idx & 15) * 8;
            ushort tmp[8];
            *(uint4*)tmp = *(const uint4*)&Bm[(size_t)(k0 + kr) * N + n0 + nc];
            #pragma unroll
            for (int j = 0; j < 8; j++) Bs[nc + j][kr] = tmp[j];
        }
        __syncthreads();

        short8 af[4], bf[4];
        #pragma unroll
        for (int t = 0; t < 4; t++) {
            af[t] = *(const short8*)&As[wm + t * 16 + (lane & 15)][(lane >> 4) * 8];
            bf[t] = *(const short8*)&Bs[wn + t * 16 + (lane & 15)][(lane >> 4) * 8];
        }
        #pragma unroll
        for (int rt = 0; rt < 4; rt++)
            #pragma unroll
            for (int ct = 0; ct < 4; ct++)
                acc[rt][ct] = __builtin_amdgcn_mfma_f32_16x16x32_bf16(af[rt], bf[ct], acc[rt][ct], 0, 0, 0);
        __syncthreads();
    }

    // D layout: col=lane&15, row=(lane>>4)*4+r  [m89/m91 verified]
    #pragma unroll
    for (int rt = 0; rt < 4; rt++)
        #pragma unroll
        for (int ct = 0; ct < 4; ct++)
            #pragma unroll
            for (int r = 0; r < 4; r++) {
                int row = m0 + wm + rt * 16 + (lane >> 4) * 4 + r;
                int col = n0 + wn + ct * 16 + (lane & 15);
                Cp[(size_t)row * ldc + col] = acc[rt][ct][r];
            }
}

// ---------------------------------------------------------------------------
// Per-(b,t): gate + ve-add, RoPE + RMSNorm. qkv row = [q(1024)|k(512)|v(512)] f32.
// Writes Q (B,NH,T,HD), K (B,NKV,T,HD), V TRANSPOSED (B,NKV,HD,T) in bf16.
// ---------------------------------------------------------------------------
__global__ __launch_bounds__(256) void qkv_post_kernel(
    const float* __restrict__ qkv, const float* __restrict__ x,
    const float* __restrict__ ve, const float* __restrict__ cosb,
    const float* __restrict__ sinb, const float* __restrict__ wgate,
    ushort* __restrict__ Qb, ushort* __restrict__ Kb, ushort* __restrict__ Vt)
{
    const int bt = blockIdx.x;
    const int b = bt >> 11, t = bt & 2047;
    const int tid = threadIdx.x;
    const int lane = tid & 63;
    const int w = tid >> 6;
    __shared__ float gateS[8];

    {
        int g = tid >> 5, i = tid & 31;
        float p = x[(size_t)bt * CC + i] * wgate[i * 8 + g];
        #pragma unroll
        for (int off = 16; off; off >>= 1) p += __shfl_down(p, off, 32);
        if (i == 0) gateS[g] = 2.f / (1.f + __expf(-p));
    }
    __syncthreads();

    const float c = cosb[t * 32 + (lane & 31)];
    const float s = sinb[t * 32 + (lane & 31)];
    for (int hh = w; hh < 24; hh += 4) {
        const float* z = &qkv[(size_t)bt * 2048 + hh * 64];
        float v = z[lane];
        float other = __shfl_xor(v, 32);
        float x1 = (lane < 32) ? v : other;
        float x2 = (lane < 32) ? other : v;
        float val = (lane < 32) ? (x1 * c + x2 * s) : (-x1 * s + x2 * c);
        float ss = val * val;
        #pragma unroll
        for (int off = 32; off; off >>= 1) ss += __shfl_xor(ss, off);
        float scale = rsqrtf(ss * (1.f / 64.f) + 1.1920929e-07f);
        ushort ob = f2bf(val * scale);
        if (hh < 16) Qb[(((size_t)b * NH + hh) * TT + t) * HD + lane] = ob;
        else         Kb[(((size_t)b * NKV + (hh - 16)) * TT + t) * HD + lane] = ob;
    }

    for (int e = tid; e < NKV * HD; e += 256) {
        int kh = e >> 6, d = e & 63;
        float v = qkv[(size_t)bt * 2048 + 1536 + e] + gateS[kh] * ve[(size_t)bt * 512 + e];
        Vt[(((size_t)b * NKV + kh) * HD + d) * TT + t] = f2bf(v);
    }
}

// ---------------------------------------------------------------------------
// Barrier-free flash attention, TRANSPOSED scores: S^T = K·Q^T so qrow lives
// in lane&15 -> softmax is in-register + 2 shuffles; O accumulated as
// O^T = V^T·P^T (alpha lane-resident). 1 wave / 32 q-rows; K prefetch;
// mask VALU only on the <=2 tiles that need it.
// ---------------------------------------------------------------------------
__global__ __launch_bounds__(64) void attn_kernel(
    const ushort* __restrict__ Qb, const ushort* __restrict__ Kb,
    const ushort* __restrict__ Vt, ushort* __restrict__ Yb,
    const int* __restrict__ winp)
{
    // heavy-first mapping: global heads (desc q), then local heads (desc q)
    const int gid = blockIdx.x;
    int b, h, qw;
    if (gid < 1024) { qw = 63 - (gid >> 4); h = (gid >> 1) & 7; b = gid & 1; }
    else { int j = gid - 1024; qw = 63 - (j >> 4); h = 8 + ((j >> 1) & 7); b = j & 1; }

    const int q0 = qw * 32;
    const int kvh = h >> 1;
    const bool local = (h >= 8);
    int window = *winp;
    if (window < 0 || window > TT) window = TT;
    const int lane = threadIdx.x;
    const int lr = lane & 15, lc = lane >> 4;

    __shared__ ushort Ps[16][72];   // P^T scratch: [qrow][key], b128-readable

    // Q B-frags: B[n=qrow][k=d]
    const ushort* qbase = &Qb[(((size_t)b * NH + h) * TT + q0) * HD];
    short8 qf[2][2];
    #pragma unroll
    for (int rt = 0; rt < 2; rt++)
        #pragma unroll
        for (int xh = 0; xh < 2; xh++)
            qf[rt][xh] = *(const short8*)&qbase[(size_t)(rt * 16 + lr) * HD + xh * 32 + lc * 8];

    float4v o[2][4] = {};           // O^T: col=qrow(lr), row=d
    float m_[2] = {-1e30f, -1e30f};
    float l_[2] = {0.f, 0.f};

    const ushort* Kbase = &Kb[((size_t)b * NKV + kvh) * TT * HD];
    const ushort* Vbase = &Vt[((size_t)b * NKV + kvh) * HD * TT];

    const int qlast = q0 + 31;
    int jstart = 0;
    if (local) { int js = q0 - window; if (js > 0) jstart = js & ~63; }

    // K A-frags for first tile: A[m=key][k=d]
    short8 kf[4][2];
    #pragma unroll
    for (int jt = 0; jt < 4; jt++) {
        const ushort* kp = &Kbase[(size_t)(jstart + jt * 16 + lr) * HD + lc * 8];
        kf[jt][0] = *(const short8*)kp;
        kf[jt][1] = *(const short8*)(kp + 32);
    }

    for (int j0 = jstart; j0 <= qlast; j0 += 64) {
        // V A-frags for this tile: A[m=d][k=key] (contiguous keys, transposed V)
        short8 vf[4][2];
        #pragma unroll
        for (int ct = 0; ct < 4; ct++) {
            const ushort* vp = &Vbase[(size_t)(ct * 16 + lr) * TT + j0 + lc * 8];
            vf[ct][0] = *(const short8*)vp;
            vf[ct][1] = *(const short8*)(vp + 32);
        }
        // prefetch next K tile
        short8 kn[4][2];
        const bool more = (j0 + 64 <= qlast);
        if (more) {
            #pragma unroll
            for (int jt = 0; jt < 4; jt++) {
                const ushort* kp = &Kbase[(size_t)(j0 + 64 + jt * 16 + lr) * HD + lc * 8];
                kn[jt][0] = *(const short8*)kp;
                kn[jt][1] = *(const short8*)(kp + 32);
            }
        }

        // S^T = K·Q^T : D[row=key][col=qrow]
        float4v st[2][4];
        #pragma unroll
        for (int jt = 0; jt < 4; jt++)
            #pragma unroll
            for (int rt = 0; rt < 2; rt++) {
                float4v z = {};
                z = __builtin_amdgcn_mfma_f32_16x16x32_bf16(kf[jt][0], qf[rt][0], z, 0, 0, 0);
                z = __builtin_amdgcn_mfma_f32_16x16x32_bf16(kf[jt][1], qf[rt][1], z, 0, 0, 0);
                st[rt][jt] = z;
            }

        const bool need_c = (j0 + 63 > q0);                       // causal edge tile
        const bool need_w = local && (j0 < qlast - window);       // window edge tile

        #pragma unroll
        for (int rt = 0; rt < 2; rt++) {
            const int qrow = q0 + rt * 16 + lr;                   // lane-resident
            float p[4][4];
            float mx = -1e30f;
            if (need_c || need_w) {
                #pragma unroll
                for (int jt = 0; jt < 4; jt++)
                    #pragma unroll
                    for (int r = 0; r < 4; r++) {
                        int key = j0 + jt * 16 + lc * 4 + r;
                        bool ok = (key <= qrow) && (!local || key >= qrow - window);
                        float v = ok ? st[rt][jt][r] * 0.125f : -1e30f;
                        p[jt][r] = v;
                        mx = fmaxf(mx, v);
                    }
            } else {
                #pragma unroll
                for (int jt = 0; jt < 4; jt++)
                    #pragma unroll
                    for (int r = 0; r < 4; r++) {
                        float v = st[rt][jt][r] * 0.125f;
                        p[jt][r] = v;
                        mx = fmaxf(mx, v);
                    }
            }
            mx = fmaxf(mx, __shfl_xor(mx, 16));
            mx = fmaxf(mx, __shfl_xor(mx, 32));
            float mnew = fmaxf(m_[rt], mx);
            float alpha = __expf(fminf(m_[rt] - mnew, 0.f));
            m_[rt] = mnew;
            float ps = 0.f;
            #pragma unroll
            for (int jt = 0; jt < 4; jt++)
                #pragma unroll
                for (int r = 0; r < 4; r++) {
                    float e = (p[jt][r] > -1e29f) ? __expf(fminf(p[jt][r] - mnew, 0.f)) : 0.f;
                    p[jt][r] = e;
                    ps += e;
                }
            ps += __shfl_xor(ps, 16);
            ps += __shfl_xor(ps, 32);
            l_[rt] = l_[rt] * alpha + ps;
            #pragma unroll
            for (int ct = 0; ct < 4; ct++)
                #pragma unroll
                for (int r = 0; r < 4; r++) o[rt][ct][r] *= alpha;

            // P^T -> LDS (packed b64 writes): Ps[qrow][key]
            #pragma unroll
            for (int jt = 0; jt < 4; jt++) {
                ushort4 u;
                u.x = f2bf(p[jt][0]); u.y = f2bf(p[jt][1]);
                u.z = f2bf(p[jt][2]); u.w = f2bf(p[jt][3]);
                *(ushort4*)&Ps[lr][jt * 16 + lc * 4] = u;
            }
            // B-frag read: B[n=qrow][k=key]
            short8 pb0 = *(const short8*)&Ps[lr][lc * 8];
            short8 pb1 = *(const short8*)&Ps[lr][32 + lc * 8];
            // O^T += V^T·P^T
            #pragma unroll
            for (int ct = 0; ct < 4; ct++) {
                o[rt][ct] = __builtin_amdgcn_mfma_f32_16x16x32_bf16(vf[ct][0], pb0, o[rt][ct], 0, 0, 0);
                o[rt][ct] = __builtin_amdgcn_mfma_f32_16x16x32_bf16(vf[ct][1], pb1, o[rt][ct], 0, 0, 0);
            }
        }

        if (more) {
            #pragma unroll
            for (int jt = 0; jt < 4; jt++) {
                kf[jt][0] = kn[jt][0];
                kf[jt][1] = kn[jt][1];
            }
        }
    }

    // normalize + write y: O^T layout -> y[b][qrow][h*64 + ct*16 + lc*4 + r]
    #pragma unroll
    for (int rt = 0; rt < 2; rt++) {
        float inv = 1.f / fmaxf(l_[rt], 1e-20f);
        int qrow = q0 + rt * 16 + lr;
        #pragma unroll
        for (int ct = 0; ct < 4; ct++) {
            ushort4 u;
            u.x = f2bf(o[rt][ct][0] * inv);
            u.y = f2bf(o[rt][ct][1] * inv);
            u.z = f2bf(o[rt][ct][2] * inv);
            u.w = f2bf(o[rt][ct][3] * inv);
            *(ushort4*)&Yb[((size_t)b * TT + qrow) * CC + h * 64 + ct * 16 + lc * 4] = u;
        }
    }
}

// ---------------------------------------------------------------------------
extern "C" void kernel_launch(void* const* d_in, const int* in_sizes, int n_in,
                              void* d_out, int out_size, void* d_ws, size_t ws_size,
                              hipStream_t stream) {
    (void)in_sizes; (void)n_in; (void)out_size; (void)ws_size;
    const float* x     = (const float*)d_in[0];
    const float* ve    = (const float*)d_in[1];
    const float* cosb  = (const float*)d_in[2];
    const float* sinb  = (const float*)d_in[3];
    const float* Wq    = (const float*)d_in[4];
    const float* Wk    = (const float*)d_in[5];
    const float* Wv    = (const float*)d_in[6];
    const float* Wproj = (const float*)d_in[7];
    const float* Wgate = (const float*)d_in[8];
    const int*   winp  = (const int*)d_in[9];
    float* out = (float*)d_out;

    char* ws = (char*)d_ws;
    float*  qkv  = (float*)ws;                      // 32 MiB (dead after qkv_post)
    ushort* Yb   = (ushort*)ws;                     // 8 MiB, overlays qkv
    ushort* xb   = (ushort*)(ws + 33554432);        // 8 MiB
    ushort* Wqkvb= (ushort*)(ws + 41943040);        // 4 MiB
    ushort* Wpb  = (ushort*)(ws + 46137344);        // 2 MiB
    ushort* Qb   = (ushort*)(ws + 48234496);        // 8 MiB
    ushort* Kb   = (ushort*)(ws + 56623104);        // 4 MiB
    ushort* Vtb  = (ushort*)(ws + 60817408);        // 4 MiB (B,NKV,HD,T)

    dim3 blk(256);
    conv_kernel<<<dim3(4096), blk, 0, stream>>>(x, xb, BB * TT * CC);
    pack_qkv_w_kernel<<<dim3(8192), blk, 0, stream>>>(Wq, Wk, Wv, Wqkvb);
    conv_kernel<<<dim3(1024), blk, 0, stream>>>(Wproj, Wpb, CC * CC);
    // fused QKV projection (f32 out, row = [q|k|v])
    gemm_kernel<<<dim3(32, 16), blk, 0, stream>>>(xb, Wqkvb, qkv, 4096, 2048, 1024, 2048);
    // gate/ve/rope/rmsnorm (+ V transpose)
    qkv_post_kernel<<<dim3(BB * TT), blk, 0, stream>>>(qkv, x, ve, cosb, sinb, Wgate, Qb, Kb, Vtb);
    // attention: 2048 single-wave blocks, heavy-first
    attn_kernel<<<dim3(2048), dim3(64), 0, stream>>>(Qb, Kb, Vtb, Yb, winp);
    // output projection -> f32 d_out (128x128 tiles, reverted)
    gemm_kernel<<<dim3(32, 8), blk, 0, stream>>>(Yb, Wpb, out, 4096, 1024, 1024, 1024);
}

// Round 5
// 255.992 us; speedup vs baseline: 1.5211x; 1.3000x over previous
//
#include <hip/hip_runtime.h>
#include <hip/hip_bf16.h>

// Problem constants (B=2, T=2048, C=1024, NH=16, NKV=8, HD=64, Q_PER_KV=2)
#define BB 2
#define TT 2048
#define CC 1024
#define NH 16
#define NKV 8
#define HD 64

typedef __attribute__((ext_vector_type(8))) short short8;   // 8 bf16 (MFMA A/B frag)
typedef __attribute__((ext_vector_type(4))) float float4v;  // MFMA C/D frag

__device__ __forceinline__ ushort f2bf(float f) {
    __hip_bfloat16 h = __float2bfloat16(f);
    union { __hip_bfloat16 h; ushort u; } v; v.h = h; return v.u;
}

// async global->LDS, 16B per lane; lptr must be wave-uniform, HW adds lane*16
__device__ __forceinline__ void gload16(const ushort* g, ushort* l) {
    __builtin_amdgcn_global_load_lds(
        (const __attribute__((address_space(1))) unsigned int*)g,
        (__attribute__((address_space(3))) unsigned int*)l, 16, 0, 0);
}

// ---------------------------------------------------------------------------
// f32 -> bf16 convert (n multiple of 4)
// ---------------------------------------------------------------------------
__global__ __launch_bounds__(256) void conv_kernel(
    const float* __restrict__ src, ushort* __restrict__ dst, int n)
{
    int i = (blockIdx.x * 256 + threadIdx.x) * 4;
    if (i + 3 < n) {
        float4 v = *(const float4*)&src[i];
        dst[i + 0] = f2bf(v.x);
        dst[i + 1] = f2bf(v.y);
        dst[i + 2] = f2bf(v.z);
        dst[i + 3] = f2bf(v.w);
    }
}

// ---------------------------------------------------------------------------
// f32 [K][N] -> bf16 [N][K] transpose via LDS 64x64 tile (one-shot, weights)
// ---------------------------------------------------------------------------
__global__ __launch_bounds__(256) void transpose_conv_kernel(
    const float* __restrict__ src, ushort* __restrict__ dst, int Kd, int Nd)
{
    __shared__ float tile[64][65];
    const int kt = blockIdx.x * 64, nt = blockIdx.y * 64;
    const int tid = threadIdx.x;
    {
        int r = tid >> 2, c = (tid & 3) * 16;
        #pragma unroll
        for (int i = 0; i < 4; i++) {
            float4 v = *(const float4*)&src[(size_t)(kt + r) * Nd + nt + c + i * 4];
            tile[r][c + i * 4 + 0] = v.x;
            tile[r][c + i * 4 + 1] = v.y;
            tile[r][c + i * 4 + 2] = v.z;
            tile[r][c + i * 4 + 3] = v.w;
        }
    }
    __syncthreads();
    {
        int n = tid >> 2, k = (tid & 3) * 16;
        #pragma unroll
        for (int i = 0; i < 2; i++) {
            ushort u[8];
            #pragma unroll
            for (int j = 0; j < 8; j++) u[j] = f2bf(tile[k + i * 8 + j][n]);
            *(uint4*)&dst[(size_t)(nt + n) * Kd + kt + k + i * 8] = *(uint4*)u;
        }
    }
}

// ---------------------------------------------------------------------------
// bf16 GEMM (m97 structure): C = A @ Bt^T. A[M][K], Bt[N][K] row-major bf16,
// C f32. Tile 128x128, BK=32, 4 waves; global_load_lds staging, no conflicts.
// ---------------------------------------------------------------------------
__global__ __launch_bounds__(256) void gemm_bt_kernel(
    const ushort* __restrict__ A, const ushort* __restrict__ Bt,
    float* __restrict__ Cp, int M, int N, int K, int ldc)
{
    __shared__ ushort As[128][32];   // [m][k] — unpadded (global_load_lds order)
    __shared__ ushort Bs[128][32];   // [n][k]

    const int m0 = blockIdx.x * 128;
    const int n0 = blockIdx.y * 128;
    const int tid = threadIdx.x;
    const int lane = tid & 63;
    const int w = tid >> 6;
    const int lr = lane & 15, lc = lane >> 4;
    const int wm = (w >> 1) * 64, wn = (w & 1) * 64;

    float4v acc[4][4] = {};

    for (int k0 = 0; k0 < K; k0 += 32) {
        // stage: wave w covers rows [w*32, w*32+32) of both tiles (2 segs each)
        #pragma unroll
        for (int s = 0; s < 2; s++) {
            int rb = w * 32 + s * 16;
            gload16(&A [(size_t)(m0 + rb + (lane >> 2)) * K + k0 + (lane & 3) * 8], &As[rb][0]);
            gload16(&Bt[(size_t)(n0 + rb + (lane >> 2)) * K + k0 + (lane & 3) * 8], &Bs[rb][0]);
        }
        __syncthreads();   // compiler emits vmcnt(0) drain before s_barrier

        short8 af[4], bf[4];
        #pragma unroll
        for (int t = 0; t < 4; t++) {
            af[t] = *(const short8*)&As[wm + t * 16 + lr][lc * 8];
            bf[t] = *(const short8*)&Bs[wn + t * 16 + lr][lc * 8];
        }
        #pragma unroll
        for (int rt = 0; rt < 4; rt++)
            #pragma unroll
            for (int ct = 0; ct < 4; ct++)
                acc[rt][ct] = __builtin_amdgcn_mfma_f32_16x16x32_bf16(af[rt], bf[ct], acc[rt][ct], 0, 0, 0);
        __syncthreads();
    }

    // D layout: col=lane&15, row=(lane>>4)*4+r  [m89/m91 verified]
    #pragma unroll
    for (int rt = 0; rt < 4; rt++)
        #pragma unroll
        for (int ct = 0; ct < 4; ct++)
            #pragma unroll
            for (int r = 0; r < 4; r++) {
                int row = m0 + wm + rt * 16 + lc * 4 + r;
                int col = n0 + wn + ct * 16 + lr;
                Cp[(size_t)row * ldc + col] = acc[rt][ct][r];
            }
}

// ---------------------------------------------------------------------------
// Per-(b,t): gate + ve-add, RoPE + RMSNorm. qkv row = [q(1024)|k(512)|v(512)] f32.
// Writes Q (B,NH,T,HD), K (B,NKV,T,HD), V TRANSPOSED (B,NKV,HD,T) in bf16.
// ---------------------------------------------------------------------------
__global__ __launch_bounds__(256) void qkv_post_kernel(
    const float* __restrict__ qkv, const float* __restrict__ x,
    const float* __restrict__ ve, const float* __restrict__ cosb,
    const float* __restrict__ sinb, const float* __restrict__ wgate,
    ushort* __restrict__ Qb, ushort* __restrict__ Kb, ushort* __restrict__ Vt)
{
    const int bt = blockIdx.x;
    const int b = bt >> 11, t = bt & 2047;
    const int tid = threadIdx.x;
    const int lane = tid & 63;
    const int w = tid >> 6;
    __shared__ float gateS[8];

    {
        int g = tid >> 5, i = tid & 31;
        float p = x[(size_t)bt * CC + i] * wgate[i * 8 + g];
        #pragma unroll
        for (int off = 16; off; off >>= 1) p += __shfl_down(p, off, 32);
        if (i == 0) gateS[g] = 2.f / (1.f + __expf(-p));
    }
    __syncthreads();

    const float c = cosb[t * 32 + (lane & 31)];
    const float s = sinb[t * 32 + (lane & 31)];
    for (int hh = w; hh < 24; hh += 4) {
        const float* z = &qkv[(size_t)bt * 2048 + hh * 64];
        float v = z[lane];
        float other = __shfl_xor(v, 32);
        float x1 = (lane < 32) ? v : other;
        float x2 = (lane < 32) ? other : v;
        float val = (lane < 32) ? (x1 * c + x2 * s) : (-x1 * s + x2 * c);
        float ss = val * val;
        #pragma unroll
        for (int off = 32; off; off >>= 1) ss += __shfl_xor(ss, off);
        float scale = rsqrtf(ss * (1.f / 64.f) + 1.1920929e-07f);
        ushort ob = f2bf(val * scale);
        if (hh < 16) Qb[(((size_t)b * NH + hh) * TT + t) * HD + lane] = ob;
        else         Kb[(((size_t)b * NKV + (hh - 16)) * TT + t) * HD + lane] = ob;
    }

    for (int e = tid; e < NKV * HD; e += 256) {
        int kh = e >> 6, d = e & 63;
        float v = qkv[(size_t)bt * 2048 + 1536 + e] + gateS[kh] * ve[(size_t)bt * 512 + e];
        Vt[(((size_t)b * NKV + kh) * HD + d) * TT + t] = f2bf(v);
    }
}

// ---------------------------------------------------------------------------
// Barrier-free flash attention, transposed scores (S^T = K·Q^T, O^T = V^T·P^T).
// 1 wave per block, 32 q-rows; K prefetch; mask VALU only on edge tiles.
// ---------------------------------------------------------------------------
__global__ __launch_bounds__(64) void attn_kernel(
    const ushort* __restrict__ Qb, const ushort* __restrict__ Kb,
    const ushort* __restrict__ Vt, ushort* __restrict__ Yb,
    const int* __restrict__ winp)
{
    const int gid = blockIdx.x;
    int b, h, qw;
    if (gid < 1024) { qw = 63 - (gid >> 4); h = (gid >> 1) & 7; b = gid & 1; }
    else { int j = gid - 1024; qw = 63 - (j >> 4); h = 8 + ((j >> 1) & 7); b = j & 1; }

    const int q0 = qw * 32;
    const int kvh = h >> 1;
    const bool local = (h >= 8);
    int window = *winp;
    if (window < 0 || window > TT) window = TT;
    const int lane = threadIdx.x;
    const int lr = lane & 15, lc = lane >> 4;

    __shared__ ushort Ps[16][72];

    const ushort* qbase = &Qb[(((size_t)b * NH + h) * TT + q0) * HD];
    short8 qf[2][2];
    #pragma unroll
    for (int rt = 0; rt < 2; rt++)
        #pragma unroll
        for (int xh = 0; xh < 2; xh++)
            qf[rt][xh] = *(const short8*)&qbase[(size_t)(rt * 16 + lr) * HD + xh * 32 + lc * 8];

    float4v o[2][4] = {};
    float m_[2] = {-1e30f, -1e30f};
    float l_[2] = {0.f, 0.f};

    const ushort* Kbase = &Kb[((size_t)b * NKV + kvh) * TT * HD];
    const ushort* Vbase = &Vt[((size_t)b * NKV + kvh) * HD * TT];

    const int qlast = q0 + 31;
    int jstart = 0;
    if (local) { int js = q0 - window; if (js > 0) jstart = js & ~63; }

    short8 kf[4][2];
    #pragma unroll
    for (int jt = 0; jt < 4; jt++) {
        const ushort* kp = &Kbase[(size_t)(jstart + jt * 16 + lr) * HD + lc * 8];
        kf[jt][0] = *(const short8*)kp;
        kf[jt][1] = *(const short8*)(kp + 32);
    }

    for (int j0 = jstart; j0 <= qlast; j0 += 64) {
        short8 vf[4][2];
        #pragma unroll
        for (int ct = 0; ct < 4; ct++) {
            const ushort* vp = &Vbase[(size_t)(ct * 16 + lr) * TT + j0 + lc * 8];
            vf[ct][0] = *(const short8*)vp;
            vf[ct][1] = *(const short8*)(vp + 32);
        }
        short8 kn[4][2];
        const bool more = (j0 + 64 <= qlast);
        if (more) {
            #pragma unroll
            for (int jt = 0; jt < 4; jt++) {
                const ushort* kp = &Kbase[(size_t)(j0 + 64 + jt * 16 + lr) * HD + lc * 8];
                kn[jt][0] = *(const short8*)kp;
                kn[jt][1] = *(const short8*)(kp + 32);
            }
        }

        float4v st[2][4];
        #pragma unroll
        for (int jt = 0; jt < 4; jt++)
            #pragma unroll
            for (int rt = 0; rt < 2; rt++) {
                float4v z = {};
                z = __builtin_amdgcn_mfma_f32_16x16x32_bf16(kf[jt][0], qf[rt][0], z, 0, 0, 0);
                z = __builtin_amdgcn_mfma_f32_16x16x32_bf16(kf[jt][1], qf[rt][1], z, 0, 0, 0);
                st[rt][jt] = z;
            }

        const bool need_c = (j0 + 63 > q0);
        const bool need_w = local && (j0 < qlast - window);

        #pragma unroll
        for (int rt = 0; rt < 2; rt++) {
            const int qrow = q0 + rt * 16 + lr;
            float p[4][4];
            float mx = -1e30f;
            if (need_c || need_w) {
                #pragma unroll
                for (int jt = 0; jt < 4; jt++)
                    #pragma unroll
                    for (int r = 0; r < 4; r++) {
                        int key = j0 + jt * 16 + lc * 4 + r;
                        bool ok = (key <= qrow) && (!local || key >= qrow - window);
                        float v = ok ? st[rt][jt][r] * 0.125f : -1e30f;
                        p[jt][r] = v;
                        mx = fmaxf(mx, v);
                    }
            } else {
                #pragma unroll
                for (int jt = 0; jt < 4; jt++)
                    #pragma unroll
                    for (int r = 0; r < 4; r++) {
                        float v = st[rt][jt][r] * 0.125f;
                        p[jt][r] = v;
                        mx = fmaxf(mx, v);
                    }
            }
            mx = fmaxf(mx, __shfl_xor(mx, 16));
            mx = fmaxf(mx, __shfl_xor(mx, 32));
            float mnew = fmaxf(m_[rt], mx);
            float alpha = __expf(fminf(m_[rt] - mnew, 0.f));
            m_[rt] = mnew;
            float ps = 0.f;
            #pragma unroll
            for (int jt = 0; jt < 4; jt++)
                #pragma unroll
                for (int r = 0; r < 4; r++) {
                    float e = (p[jt][r] > -1e29f) ? __expf(fminf(p[jt][r] - mnew, 0.f)) : 0.f;
                    p[jt][r] = e;
                    ps += e;
                }
            ps += __shfl_xor(ps, 16);
            ps += __shfl_xor(ps, 32);
            l_[rt] = l_[rt] * alpha + ps;
            #pragma unroll
            for (int ct = 0; ct < 4; ct++)
                #pragma unroll
                for (int r = 0; r < 4; r++) o[rt][ct][r] *= alpha;

            #pragma unroll
            for (int jt = 0; jt < 4; jt++) {
                ushort4 u;
                u.x = f2bf(p[jt][0]); u.y = f2bf(p[jt][1]);
                u.z = f2bf(p[jt][2]); u.w = f2bf(p[jt][3]);
                *(ushort4*)&Ps[lr][jt * 16 + lc * 4] = u;
            }
            short8 pb0 = *(const short8*)&Ps[lr][lc * 8];
            short8 pb1 = *(const short8*)&Ps[lr][32 + lc * 8];
            #pragma unroll
            for (int ct = 0; ct < 4; ct++) {
                o[rt][ct] = __builtin_amdgcn_mfma_f32_16x16x32_bf16(vf[ct][0], pb0, o[rt][ct], 0, 0, 0);
                o[rt][ct] = __builtin_amdgcn_mfma_f32_16x16x32_bf16(vf[ct][1], pb1, o[rt][ct], 0, 0, 0);
            }
        }

        if (more) {
            #pragma unroll
            for (int jt = 0; jt < 4; jt++) {
                kf[jt][0] = kn[jt][0];
                kf[jt][1] = kn[jt][1];
            }
        }
    }

    #pragma unroll
    for (int rt = 0; rt < 2; rt++) {
        float inv = 1.f / fmaxf(l_[rt], 1e-20f);
        int qrow = q0 + rt * 16 + lr;
        #pragma unroll
        for (int ct = 0; ct < 4; ct++) {
            ushort4 u;
            u.x = f2bf(o[rt][ct][0] * inv);
            u.y = f2bf(o[rt][ct][1] * inv);
            u.z = f2bf(o[rt][ct][2] * inv);
            u.w = f2bf(o[rt][ct][3] * inv);
            *(ushort4*)&Yb[((size_t)b * TT + qrow) * CC + h * 64 + ct * 16 + lc * 4] = u;
        }
    }
}

// ---------------------------------------------------------------------------
extern "C" void kernel_launch(void* const* d_in, const int* in_sizes, int n_in,
                              void* d_out, int out_size, void* d_ws, size_t ws_size,
                              hipStream_t stream) {
    (void)in_sizes; (void)n_in; (void)out_size; (void)ws_size;
    const float* x     = (const float*)d_in[0];
    const float* ve    = (const float*)d_in[1];
    const float* cosb  = (const float*)d_in[2];
    const float* sinb  = (const float*)d_in[3];
    const float* Wq    = (const float*)d_in[4];
    const float* Wk    = (const float*)d_in[5];
    const float* Wv    = (const float*)d_in[6];
    const float* Wproj = (const float*)d_in[7];
    const float* Wgate = (const float*)d_in[8];
    const int*   winp  = (const int*)d_in[9];
    float* out = (float*)d_out;

    char* ws = (char*)d_ws;
    float*  qkv   = (float*)ws;                      // 32 MiB (dead after qkv_post)
    ushort* Yb    = (ushort*)ws;                     // 8 MiB, overlays qkv
    ushort* xb    = (ushort*)(ws + 33554432);        // 8 MiB
    ushort* WqkvT = (ushort*)(ws + 41943040);        // 4 MiB: [2048][1024] = W^T
    ushort* WpT   = (ushort*)(ws + 46137344);        // 2 MiB: [1024][1024] = Wproj^T
    ushort* Qb    = (ushort*)(ws + 48234496);        // 8 MiB
    ushort* Kb    = (ushort*)(ws + 56623104);        // 4 MiB
    ushort* Vtb   = (ushort*)(ws + 60817408);        // 4 MiB (B,NKV,HD,T)

    dim3 blk(256);
    conv_kernel<<<dim3(4096), blk, 0, stream>>>(x, xb, BB * TT * CC);
    // weight transposes (one-shot): dst[n][k]
    transpose_conv_kernel<<<dim3(16, 16), blk, 0, stream>>>(Wq, WqkvT, 1024, 1024);
    transpose_conv_kernel<<<dim3(16, 8), blk, 0, stream>>>(Wk, WqkvT + (size_t)1024 * 1024, 1024, 512);
    transpose_conv_kernel<<<dim3(16, 8), blk, 0, stream>>>(Wv, WqkvT + (size_t)1536 * 1024, 1024, 512);
    transpose_conv_kernel<<<dim3(16, 16), blk, 0, stream>>>(Wproj, WpT, 1024, 1024);
    // fused QKV projection (f32 out, row = [q|k|v])
    gemm_bt_kernel<<<dim3(32, 16), blk, 0, stream>>>(xb, WqkvT, qkv, 4096, 2048, 1024, 2048);
    // gate/ve/rope/rmsnorm (+ V transpose)
    qkv_post_kernel<<<dim3(BB * TT), blk, 0, stream>>>(qkv, x, ve, cosb, sinb, Wgate, Qb, Kb, Vtb);
    // attention: 2048 single-wave blocks, heavy-first
    attn_kernel<<<dim3(2048), dim3(64), 0, stream>>>(Qb, Kb, Vtb, Yb, winp);
    // output projection -> f32 d_out
    gemm_bt_kernel<<<dim3(32, 8), blk, 0, stream>>>(Yb, WpT, out, 4096, 1024, 1024, 1024);
}

// Round 6
// 245.335 us; speedup vs baseline: 1.5872x; 1.0434x over previous
//
#include <hip/hip_runtime.h>
#include <hip/hip_bf16.h>

// Problem constants (B=2, T=2048, C=1024, NH=16, NKV=8, HD=64, Q_PER_KV=2)
#define BB 2
#define TT 2048
#define CC 1024
#define NH 16
#define NKV 8
#define HD 64

typedef __attribute__((ext_vector_type(8))) short short8;   // 8 bf16 (MFMA A/B frag)
typedef __attribute__((ext_vector_type(4))) float float4v;  // MFMA C/D frag

__device__ __forceinline__ ushort f2bf(float f) {
    __hip_bfloat16 h = __float2bfloat16(f);
    union { __hip_bfloat16 h; ushort u; } v; v.h = h; return v.u;
}

// async global->LDS, 16B per lane; lptr must be wave-uniform, HW adds lane*16
__device__ __forceinline__ void gload16(const ushort* g, ushort* l) {
    __builtin_amdgcn_global_load_lds(
        (const __attribute__((address_space(1))) unsigned int*)g,
        (__attribute__((address_space(3))) unsigned int*)l, 16, 0, 0);
}

// ---------------------------------------------------------------------------
// f32 -> bf16 convert (n multiple of 4)
// ---------------------------------------------------------------------------
__global__ __launch_bounds__(256) void conv_kernel(
    const float* __restrict__ src, ushort* __restrict__ dst, int n)
{
    int i = (blockIdx.x * 256 + threadIdx.x) * 4;
    if (i + 3 < n) {
        float4 v = *(const float4*)&src[i];
        dst[i + 0] = f2bf(v.x);
        dst[i + 1] = f2bf(v.y);
        dst[i + 2] = f2bf(v.z);
        dst[i + 3] = f2bf(v.w);
    }
}

// ---------------------------------------------------------------------------
// f32 [K][N] -> bf16 [N][K] transpose via LDS 64x64 tile (one-shot, weights)
// ---------------------------------------------------------------------------
__global__ __launch_bounds__(256) void transpose_conv_kernel(
    const float* __restrict__ src, ushort* __restrict__ dst, int Kd, int Nd)
{
    __shared__ float tile[64][65];
    const int kt = blockIdx.x * 64, nt = blockIdx.y * 64;
    const int tid = threadIdx.x;
    {
        int r = tid >> 2, c = (tid & 3) * 16;
        #pragma unroll
        for (int i = 0; i < 4; i++) {
            float4 v = *(const float4*)&src[(size_t)(kt + r) * Nd + nt + c + i * 4];
            tile[r][c + i * 4 + 0] = v.x;
            tile[r][c + i * 4 + 1] = v.y;
            tile[r][c + i * 4 + 2] = v.z;
            tile[r][c + i * 4 + 3] = v.w;
        }
    }
    __syncthreads();
    {
        int n = tid >> 2, k = (tid & 3) * 16;
        #pragma unroll
        for (int i = 0; i < 2; i++) {
            ushort u[8];
            #pragma unroll
            for (int j = 0; j < 8; j++) u[j] = f2bf(tile[k + i * 8 + j][n]);
            *(uint4*)&dst[(size_t)(nt + n) * Kd + kt + k + i * 8] = *(uint4*)u;
        }
    }
}

// ---------------------------------------------------------------------------
// bf16 GEMM (m97 structure): C = A @ Bt^T. A[M][K], Bt[N][K] row-major bf16,
// C f32. Tile 128x128, BK=32, 4 waves; global_load_lds staging, no conflicts.
// ---------------------------------------------------------------------------
__global__ __launch_bounds__(256) void gemm_bt_kernel(
    const ushort* __restrict__ A, const ushort* __restrict__ Bt,
    float* __restrict__ Cp, int M, int N, int K, int ldc)
{
    __shared__ ushort As[128][32];   // [m][k] — unpadded (global_load_lds order)
    __shared__ ushort Bs[128][32];   // [n][k]

    const int m0 = blockIdx.x * 128;
    const int n0 = blockIdx.y * 128;
    const int tid = threadIdx.x;
    const int lane = tid & 63;
    const int w = tid >> 6;
    const int lr = lane & 15, lc = lane >> 4;
    const int wm = (w >> 1) * 64, wn = (w & 1) * 64;

    float4v acc[4][4] = {};

    for (int k0 = 0; k0 < K; k0 += 32) {
        #pragma unroll
        for (int s = 0; s < 2; s++) {
            int rb = w * 32 + s * 16;
            gload16(&A [(size_t)(m0 + rb + (lane >> 2)) * K + k0 + (lane & 3) * 8], &As[rb][0]);
            gload16(&Bt[(size_t)(n0 + rb + (lane >> 2)) * K + k0 + (lane & 3) * 8], &Bs[rb][0]);
        }
        __syncthreads();

        short8 af[4], bf[4];
        #pragma unroll
        for (int t = 0; t < 4; t++) {
            af[t] = *(const short8*)&As[wm + t * 16 + lr][lc * 8];
            bf[t] = *(const short8*)&Bs[wn + t * 16 + lr][lc * 8];
        }
        #pragma unroll
        for (int rt = 0; rt < 4; rt++)
            #pragma unroll
            for (int ct = 0; ct < 4; ct++)
                acc[rt][ct] = __builtin_amdgcn_mfma_f32_16x16x32_bf16(af[rt], bf[ct], acc[rt][ct], 0, 0, 0);
        __syncthreads();
    }

    #pragma unroll
    for (int rt = 0; rt < 4; rt++)
        #pragma unroll
        for (int ct = 0; ct < 4; ct++)
            #pragma unroll
            for (int r = 0; r < 4; r++) {
                int row = m0 + wm + rt * 16 + lc * 4 + r;
                int col = n0 + wn + ct * 16 + lr;
                Cp[(size_t)row * ldc + col] = acc[rt][ct][r];
            }
}

// ---------------------------------------------------------------------------
// Per-(b,t): gate + ve-add, RoPE + RMSNorm. qkv row = [q(1024)|k(512)|v(512)] f32.
// Writes Q (B,NH,T,HD), K (B,NKV,T,HD), V TRANSPOSED (B,NKV,HD,T) in bf16.
// ---------------------------------------------------------------------------
__global__ __launch_bounds__(256) void qkv_post_kernel(
    const float* __restrict__ qkv, const float* __restrict__ x,
    const float* __restrict__ ve, const float* __restrict__ cosb,
    const float* __restrict__ sinb, const float* __restrict__ wgate,
    ushort* __restrict__ Qb, ushort* __restrict__ Kb, ushort* __restrict__ Vt)
{
    const int bt = blockIdx.x;
    const int b = bt >> 11, t = bt & 2047;
    const int tid = threadIdx.x;
    const int lane = tid & 63;
    const int w = tid >> 6;
    __shared__ float gateS[8];

    {
        int g = tid >> 5, i = tid & 31;
        float p = x[(size_t)bt * CC + i] * wgate[i * 8 + g];
        #pragma unroll
        for (int off = 16; off; off >>= 1) p += __shfl_down(p, off, 32);
        if (i == 0) gateS[g] = 2.f / (1.f + __expf(-p));
    }
    __syncthreads();

    const float c = cosb[t * 32 + (lane & 31)];
    const float s = sinb[t * 32 + (lane & 31)];
    for (int hh = w; hh < 24; hh += 4) {
        const float* z = &qkv[(size_t)bt * 2048 + hh * 64];
        float v = z[lane];
        float other = __shfl_xor(v, 32);
        float x1 = (lane < 32) ? v : other;
        float x2 = (lane < 32) ? other : v;
        float val = (lane < 32) ? (x1 * c + x2 * s) : (-x1 * s + x2 * c);
        float ss = val * val;
        #pragma unroll
        for (int off = 32; off; off >>= 1) ss += __shfl_xor(ss, off);
        float scale = rsqrtf(ss * (1.f / 64.f) + 1.1920929e-07f);
        ushort ob = f2bf(val * scale);
        if (hh < 16) Qb[(((size_t)b * NH + hh) * TT + t) * HD + lane] = ob;
        else         Kb[(((size_t)b * NKV + (hh - 16)) * TT + t) * HD + lane] = ob;
    }

    for (int e = tid; e < NKV * HD; e += 256) {
        int kh = e >> 6, d = e & 63;
        float v = qkv[(size_t)bt * 2048 + 1536 + e] + gateS[kh] * ve[(size_t)bt * 512 + e];
        Vt[(((size_t)b * NKV + kh) * HD + d) * TT + t] = f2bf(v);
    }
}

// ---------------------------------------------------------------------------
// Split-KV flash attention: block = 4 waves on one (b,h,32q) tile; wave w
// stripes key tiles (jstart + w*64, stride 256) with private (m,l,O^T);
// two-phase LDS merge at the end. Transposed scores as in round 5.
// ---------------------------------------------------------------------------
__global__ __launch_bounds__(256) void attn_kernel(
    const ushort* __restrict__ Qb, const ushort* __restrict__ Kb,
    const ushort* __restrict__ Vt, ushort* __restrict__ Yb,
    const int* __restrict__ winp)
{
    const int gid = blockIdx.x;
    int b, h, qw;
    if (gid < 1024) { qw = 63 - (gid >> 4); h = (gid >> 1) & 7; b = gid & 1; }
    else { int j = gid - 1024; qw = 63 - (j >> 4); h = 8 + ((j >> 1) & 7); b = j & 1; }

    const int q0 = qw * 32;
    const int kvh = h >> 1;
    const bool local = (h >= 8);
    int window = *winp;
    if (window < 0 || window > TT) window = TT;
    const int tid = threadIdx.x;
    const int w = tid >> 6;
    const int lane = tid & 63;
    const int lr = lane & 15, lc = lane >> 4;

    __shared__ ushort Ps[4][16][72];        // per-wave P^T scratch
    __shared__ float4v Ol[4][4][64];        // [wave][ct][lane] for current rt phase
    __shared__ float Ml[4][16], Ll[4][16];  // per-wave m,l for current rt phase

    const ushort* qbase = &Qb[(((size_t)b * NH + h) * TT + q0) * HD];
    short8 qf[2][2];
    #pragma unroll
    for (int rt = 0; rt < 2; rt++)
        #pragma unroll
        for (int xh = 0; xh < 2; xh++)
            qf[rt][xh] = *(const short8*)&qbase[(size_t)(rt * 16 + lr) * HD + xh * 32 + lc * 8];

    float4v o[2][4] = {};
    float m_[2] = {-1e30f, -1e30f};
    float l_[2] = {0.f, 0.f};

    const ushort* Kbase = &Kb[((size_t)b * NKV + kvh) * TT * HD];
    const ushort* Vbase = &Vt[((size_t)b * NKV + kvh) * HD * TT];

    const int qlast = q0 + 31;
    int jstart = 0;
    if (local) { int js = q0 - window; if (js > 0) jstart = js & ~63; }
    const int j0first = jstart + w * 64;    // this wave's first key tile

    short8 kf[4][2];
    if (j0first <= qlast) {
        #pragma unroll
        for (int jt = 0; jt < 4; jt++) {
            const ushort* kp = &Kbase[(size_t)(j0first + jt * 16 + lr) * HD + lc * 8];
            kf[jt][0] = *(const short8*)kp;
            kf[jt][1] = *(const short8*)(kp + 32);
        }
    }

    for (int j0 = j0first; j0 <= qlast; j0 += 256) {
        short8 vf[4][2];
        #pragma unroll
        for (int ct = 0; ct < 4; ct++) {
            const ushort* vp = &Vbase[(size_t)(ct * 16 + lr) * TT + j0 + lc * 8];
            vf[ct][0] = *(const short8*)vp;
            vf[ct][1] = *(const short8*)(vp + 32);
        }
        short8 kn[4][2];
        const bool more = (j0 + 256 <= qlast);
        if (more) {
            #pragma unroll
            for (int jt = 0; jt < 4; jt++) {
                const ushort* kp = &Kbase[(size_t)(j0 + 256 + jt * 16 + lr) * HD + lc * 8];
                kn[jt][0] = *(const short8*)kp;
                kn[jt][1] = *(const short8*)(kp + 32);
            }
        }

        float4v st[2][4];
        #pragma unroll
        for (int jt = 0; jt < 4; jt++)
            #pragma unroll
            for (int rt = 0; rt < 2; rt++) {
                float4v z = {};
                z = __builtin_amdgcn_mfma_f32_16x16x32_bf16(kf[jt][0], qf[rt][0], z, 0, 0, 0);
                z = __builtin_amdgcn_mfma_f32_16x16x32_bf16(kf[jt][1], qf[rt][1], z, 0, 0, 0);
                st[rt][jt] = z;
            }

        const bool need_c = (j0 + 63 > q0);
        const bool need_w = local && (j0 < qlast - window);

        #pragma unroll
        for (int rt = 0; rt < 2; rt++) {
            const int qrow = q0 + rt * 16 + lr;
            float p[4][4];
            float mx = -1e30f;
            if (need_c || need_w) {
                #pragma unroll
                for (int jt = 0; jt < 4; jt++)
                    #pragma unroll
                    for (int r = 0; r < 4; r++) {
                        int key = j0 + jt * 16 + lc * 4 + r;
                        bool ok = (key <= qrow) && (!local || key >= qrow - window);
                        float v = ok ? st[rt][jt][r] * 0.125f : -1e30f;
                        p[jt][r] = v;
                        mx = fmaxf(mx, v);
                    }
            } else {
                #pragma unroll
                for (int jt = 0; jt < 4; jt++)
                    #pragma unroll
                    for (int r = 0; r < 4; r++) {
                        float v = st[rt][jt][r] * 0.125f;
                        p[jt][r] = v;
                        mx = fmaxf(mx, v);
                    }
            }
            mx = fmaxf(mx, __shfl_xor(mx, 16));
            mx = fmaxf(mx, __shfl_xor(mx, 32));
            float mnew = fmaxf(m_[rt], mx);
            float alpha = __expf(fminf(m_[rt] - mnew, 0.f));
            m_[rt] = mnew;
            float ps = 0.f;
            #pragma unroll
            for (int jt = 0; jt < 4; jt++)
                #pragma unroll
                for (int r = 0; r < 4; r++) {
                    float e = (p[jt][r] > -1e29f) ? __expf(fminf(p[jt][r] - mnew, 0.f)) : 0.f;
                    p[jt][r] = e;
                    ps += e;
                }
            ps += __shfl_xor(ps, 16);
            ps += __shfl_xor(ps, 32);
            l_[rt] = l_[rt] * alpha + ps;
            #pragma unroll
            for (int ct = 0; ct < 4; ct++)
                #pragma unroll
                for (int r = 0; r < 4; r++) o[rt][ct][r] *= alpha;

            #pragma unroll
            for (int jt = 0; jt < 4; jt++) {
                ushort4 u;
                u.x = f2bf(p[jt][0]); u.y = f2bf(p[jt][1]);
                u.z = f2bf(p[jt][2]); u.w = f2bf(p[jt][3]);
                *(ushort4*)&Ps[w][lr][jt * 16 + lc * 4] = u;
            }
            short8 pb0 = *(const short8*)&Ps[w][lr][lc * 8];
            short8 pb1 = *(const short8*)&Ps[w][lr][32 + lc * 8];
            #pragma unroll
            for (int ct = 0; ct < 4; ct++) {
                o[rt][ct] = __builtin_amdgcn_mfma_f32_16x16x32_bf16(vf[ct][0], pb0, o[rt][ct], 0, 0, 0);
                o[rt][ct] = __builtin_amdgcn_mfma_f32_16x16x32_bf16(vf[ct][1], pb1, o[rt][ct], 0, 0, 0);
            }
        }

        if (more) {
            #pragma unroll
            for (int jt = 0; jt < 4; jt++) {
                kf[jt][0] = kn[jt][0];
                kf[jt][1] = kn[jt][1];
            }
        }
    }

    // ---- two-phase merge across the 4 key-stripe waves ----
    #pragma unroll
    for (int rt = 0; rt < 2; rt++) {
        #pragma unroll
        for (int ct = 0; ct < 4; ct++) Ol[w][ct][lane] = o[rt][ct];
        if (lc == 0) { Ml[w][lr] = m_[rt]; Ll[w][lr] = l_[rt]; }
        __syncthreads();

        // wave w merges quadrant ct=w for this rt
        {
            const int ct = w;
            float mmax = fmaxf(fmaxf(Ml[0][lr], Ml[1][lr]), fmaxf(Ml[2][lr], Ml[3][lr]));
            float f0 = __expf(fminf(Ml[0][lr] - mmax, 0.f));
            float f1 = __expf(fminf(Ml[1][lr] - mmax, 0.f));
            float f2 = __expf(fminf(Ml[2][lr] - mmax, 0.f));
            float f3 = __expf(fminf(Ml[3][lr] - mmax, 0.f));
            float ltot = f0 * Ll[0][lr] + f1 * Ll[1][lr] + f2 * Ll[2][lr] + f3 * Ll[3][lr];
            float inv = 1.f / fmaxf(ltot, 1e-20f);
            float4v a0 = Ol[0][ct][lane], a1 = Ol[1][ct][lane];
            float4v a2 = Ol[2][ct][lane], a3 = Ol[3][ct][lane];
            int qrow = q0 + rt * 16 + lr;
            ushort4 u;
            float v0 = (f0 * a0[0] + f1 * a1[0] + f2 * a2[0] + f3 * a3[0]) * inv;
            float v1 = (f0 * a0[1] + f1 * a1[1] + f2 * a2[1] + f3 * a3[1]) * inv;
            float v2 = (f0 * a0[2] + f1 * a1[2] + f2 * a2[2] + f3 * a3[2]) * inv;
            float v3 = (f0 * a0[3] + f1 * a1[3] + f2 * a2[3] + f3 * a3[3]) * inv;
            u.x = f2bf(v0); u.y = f2bf(v1); u.z = f2bf(v2); u.w = f2bf(v3);
            *(ushort4*)&Yb[((size_t)b * TT + qrow) * CC + h * 64 + ct * 16 + lc * 4] = u;
        }
        if (rt == 0) __syncthreads();   // protect Ol/Ml/Ll before phase 2 overwrite
    }
}

// ---------------------------------------------------------------------------
extern "C" void kernel_launch(void* const* d_in, const int* in_sizes, int n_in,
                              void* d_out, int out_size, void* d_ws, size_t ws_size,
                              hipStream_t stream) {
    (void)in_sizes; (void)n_in; (void)out_size; (void)ws_size;
    const float* x     = (const float*)d_in[0];
    const float* ve    = (const float*)d_in[1];
    const float* cosb  = (const float*)d_in[2];
    const float* sinb  = (const float*)d_in[3];
    const float* Wq    = (const float*)d_in[4];
    const float* Wk    = (const float*)d_in[5];
    const float* Wv    = (const float*)d_in[6];
    const float* Wproj = (const float*)d_in[7];
    const float* Wgate = (const float*)d_in[8];
    const int*   winp  = (const int*)d_in[9];
    float* out = (float*)d_out;

    char* ws = (char*)d_ws;
    float*  qkv   = (float*)ws;                      // 32 MiB (dead after qkv_post)
    ushort* Yb    = (ushort*)ws;                     // 8 MiB, overlays qkv
    ushort* xb    = (ushort*)(ws + 33554432);        // 8 MiB
    ushort* WqkvT = (ushort*)(ws + 41943040);        // 4 MiB: [2048][1024] = W^T
    ushort* WpT   = (ushort*)(ws + 46137344);        // 2 MiB: [1024][1024] = Wproj^T
    ushort* Qb    = (ushort*)(ws + 48234496);        // 8 MiB
    ushort* Kb    = (ushort*)(ws + 56623104);        // 4 MiB
    ushort* Vtb   = (ushort*)(ws + 60817408);        // 4 MiB (B,NKV,HD,T)

    dim3 blk(256);
    conv_kernel<<<dim3(4096), blk, 0, stream>>>(x, xb, BB * TT * CC);
    transpose_conv_kernel<<<dim3(16, 16), blk, 0, stream>>>(Wq, WqkvT, 1024, 1024);
    transpose_conv_kernel<<<dim3(16, 8), blk, 0, stream>>>(Wk, WqkvT + (size_t)1024 * 1024, 1024, 512);
    transpose_conv_kernel<<<dim3(16, 8), blk, 0, stream>>>(Wv, WqkvT + (size_t)1536 * 1024, 1024, 512);
    transpose_conv_kernel<<<dim3(16, 16), blk, 0, stream>>>(Wproj, WpT, 1024, 1024);
    gemm_bt_kernel<<<dim3(32, 16), blk, 0, stream>>>(xb, WqkvT, qkv, 4096, 2048, 1024, 2048);
    qkv_post_kernel<<<dim3(BB * TT), blk, 0, stream>>>(qkv, x, ve, cosb, sinb, Wgate, Qb, Kb, Vtb);
    // attention: 2048 blocks x 4 key-stripe waves, heavy-first
    attn_kernel<<<dim3(2048), blk, 0, stream>>>(Qb, Kb, Vtb, Yb, winp);
    gemm_bt_kernel<<<dim3(32, 8), blk, 0, stream>>>(Yb, WpT, out, 4096, 1024, 1024, 1024);
}

// Round 7
// 244.556 us; speedup vs baseline: 1.5923x; 1.0032x over previous
//
#include <hip/hip_runtime.h>
#include <hip/hip_bf16.h>

// Problem constants (B=2, T=2048, C=1024, NH=16, NKV=8, HD=64, Q_PER_KV=2)
#define BB 2
#define TT 2048
#define CC 1024
#define NH 16
#define NKV 8
#define HD 64

typedef __attribute__((ext_vector_type(8))) short short8;   // 8 bf16 (MFMA A/B frag)
typedef __attribute__((ext_vector_type(4))) float float4v;  // MFMA C/D frag

__device__ __forceinline__ ushort f2bf(float f) {
    __hip_bfloat16 h = __float2bfloat16(f);
    union { __hip_bfloat16 h; ushort u; } v; v.h = h; return v.u;
}

// async global->LDS, 16B per lane; lptr must be wave-uniform, HW adds lane*16
__device__ __forceinline__ void gload16(const ushort* g, ushort* l) {
    __builtin_amdgcn_global_load_lds(
        (const __attribute__((address_space(1))) unsigned int*)g,
        (__attribute__((address_space(3))) unsigned int*)l, 16, 0, 0);
}

// ---------------------------------------------------------------------------
// f32 -> bf16 convert (n multiple of 4)
// ---------------------------------------------------------------------------
__global__ __launch_bounds__(256) void conv_kernel(
    const float* __restrict__ src, ushort* __restrict__ dst, int n)
{
    int i = (blockIdx.x * 256 + threadIdx.x) * 4;
    if (i + 3 < n) {
        float4 v = *(const float4*)&src[i];
        dst[i + 0] = f2bf(v.x);
        dst[i + 1] = f2bf(v.y);
        dst[i + 2] = f2bf(v.z);
        dst[i + 3] = f2bf(v.w);
    }
}

// ---------------------------------------------------------------------------
// f32 [K][N] -> bf16 [N][K] transpose via LDS 64x64 tile (one-shot, weights)
// ---------------------------------------------------------------------------
__global__ __launch_bounds__(256) void transpose_conv_kernel(
    const float* __restrict__ src, ushort* __restrict__ dst, int Kd, int Nd)
{
    __shared__ float tile[64][65];
    const int kt = blockIdx.x * 64, nt = blockIdx.y * 64;
    const int tid = threadIdx.x;
    {
        int r = tid >> 2, c = (tid & 3) * 16;
        #pragma unroll
        for (int i = 0; i < 4; i++) {
            float4 v = *(const float4*)&src[(size_t)(kt + r) * Nd + nt + c + i * 4];
            tile[r][c + i * 4 + 0] = v.x;
            tile[r][c + i * 4 + 1] = v.y;
            tile[r][c + i * 4 + 2] = v.z;
            tile[r][c + i * 4 + 3] = v.w;
        }
    }
    __syncthreads();
    {
        int n = tid >> 2, k = (tid & 3) * 16;
        #pragma unroll
        for (int i = 0; i < 2; i++) {
            ushort u[8];
            #pragma unroll
            for (int j = 0; j < 8; j++) u[j] = f2bf(tile[k + i * 8 + j][n]);
            *(uint4*)&dst[(size_t)(nt + n) * Kd + kt + k + i * 8] = *(uint4*)u;
        }
    }
}

// ---------------------------------------------------------------------------
// bf16 GEMM (m97 structure): C = A @ Bt^T. A[M][K], Bt[N][K] row-major bf16,
// C f32. Tile 128x128, BK=32, 4 waves; global_load_lds staging, no conflicts.
// ---------------------------------------------------------------------------
__global__ __launch_bounds__(256) void gemm_bt_kernel(
    const ushort* __restrict__ A, const ushort* __restrict__ Bt,
    float* __restrict__ Cp, int M, int N, int K, int ldc)
{
    __shared__ ushort As[128][32];   // [m][k] — unpadded (global_load_lds order)
    __shared__ ushort Bs[128][32];   // [n][k]

    const int m0 = blockIdx.x * 128;
    const int n0 = blockIdx.y * 128;
    const int tid = threadIdx.x;
    const int lane = tid & 63;
    const int w = tid >> 6;
    const int lr = lane & 15, lc = lane >> 4;
    const int wm = (w >> 1) * 64, wn = (w & 1) * 64;

    float4v acc[4][4] = {};

    for (int k0 = 0; k0 < K; k0 += 32) {
        #pragma unroll
        for (int s = 0; s < 2; s++) {
            int rb = w * 32 + s * 16;
            gload16(&A [(size_t)(m0 + rb + (lane >> 2)) * K + k0 + (lane & 3) * 8], &As[rb][0]);
            gload16(&Bt[(size_t)(n0 + rb + (lane >> 2)) * K + k0 + (lane & 3) * 8], &Bs[rb][0]);
        }
        __syncthreads();

        short8 af[4], bf[4];
        #pragma unroll
        for (int t = 0; t < 4; t++) {
            af[t] = *(const short8*)&As[wm + t * 16 + lr][lc * 8];
            bf[t] = *(const short8*)&Bs[wn + t * 16 + lr][lc * 8];
        }
        #pragma unroll
        for (int rt = 0; rt < 4; rt++)
            #pragma unroll
            for (int ct = 0; ct < 4; ct++)
                acc[rt][ct] = __builtin_amdgcn_mfma_f32_16x16x32_bf16(af[rt], bf[ct], acc[rt][ct], 0, 0, 0);
        __syncthreads();
    }

    #pragma unroll
    for (int rt = 0; rt < 4; rt++)
        #pragma unroll
        for (int ct = 0; ct < 4; ct++)
            #pragma unroll
            for (int r = 0; r < 4; r++) {
                int row = m0 + wm + rt * 16 + lc * 4 + r;
                int col = n0 + wn + ct * 16 + lr;
                Cp[(size_t)row * ldc + col] = acc[rt][ct][r];
            }
}

// ---------------------------------------------------------------------------
// Per-(b,t): gate + ve-add, RoPE + RMSNorm. qkv row = [q(1024)|k(512)|v(512)] f32.
// Writes Q (B,NH,T,HD), K (B,NKV,T,HD), V TRANSPOSED (B,NKV,HD,T) in bf16.
// ---------------------------------------------------------------------------
__global__ __launch_bounds__(256) void qkv_post_kernel(
    const float* __restrict__ qkv, const float* __restrict__ x,
    const float* __restrict__ ve, const float* __restrict__ cosb,
    const float* __restrict__ sinb, const float* __restrict__ wgate,
    ushort* __restrict__ Qb, ushort* __restrict__ Kb, ushort* __restrict__ Vt)
{
    const int bt = blockIdx.x;
    const int b = bt >> 11, t = bt & 2047;
    const int tid = threadIdx.x;
    const int lane = tid & 63;
    const int w = tid >> 6;
    __shared__ float gateS[8];

    {
        int g = tid >> 5, i = tid & 31;
        float p = x[(size_t)bt * CC + i] * wgate[i * 8 + g];
        #pragma unroll
        for (int off = 16; off; off >>= 1) p += __shfl_down(p, off, 32);
        if (i == 0) gateS[g] = 2.f / (1.f + __expf(-p));
    }
    __syncthreads();

    const float c = cosb[t * 32 + (lane & 31)];
    const float s = sinb[t * 32 + (lane & 31)];
    for (int hh = w; hh < 24; hh += 4) {
        const float* z = &qkv[(size_t)bt * 2048 + hh * 64];
        float v = z[lane];
        float other = __shfl_xor(v, 32);
        float x1 = (lane < 32) ? v : other;
        float x2 = (lane < 32) ? other : v;
        float val = (lane < 32) ? (x1 * c + x2 * s) : (-x1 * s + x2 * c);
        float ss = val * val;
        #pragma unroll
        for (int off = 32; off; off >>= 1) ss += __shfl_xor(ss, off);
        float scale = rsqrtf(ss * (1.f / 64.f) + 1.1920929e-07f);
        ushort ob = f2bf(val * scale);
        if (hh < 16) Qb[(((size_t)b * NH + hh) * TT + t) * HD + lane] = ob;
        else         Kb[(((size_t)b * NKV + (hh - 16)) * TT + t) * HD + lane] = ob;
    }

    for (int e = tid; e < NKV * HD; e += 256) {
        int kh = e >> 6, d = e & 63;
        float v = qkv[(size_t)bt * 2048 + 1536 + e] + gateS[kh] * ve[(size_t)bt * 512 + e];
        Vt[(((size_t)b * NKV + kh) * HD + d) * TT + t] = f2bf(v);
    }
}

// ---------------------------------------------------------------------------
// Split-KV flash attention, NO online softmax: q,k are RMS-normalized so
// |s| = |q·k|/8 <= 8 -> exp(s) <= 2981 and row sums <= ~6e6: f32-safe
// unnormalized accumulation. p = exp(s) (0 if masked); l = lane-local tree
// sum; O^T += V^T·P^T. No max-tracking, no rescale, no per-tile shuffles.
// 4 waves stripe key tiles; merge = exact plain sums (Sigma O / Sigma l).
// ---------------------------------------------------------------------------
__global__ __launch_bounds__(256) void attn_kernel(
    const ushort* __restrict__ Qb, const ushort* __restrict__ Kb,
    const ushort* __restrict__ Vt, ushort* __restrict__ Yb,
    const int* __restrict__ winp)
{
    const int gid = blockIdx.x;
    int b, h, qw;
    if (gid < 1024) { qw = 63 - (gid >> 4); h = (gid >> 1) & 7; b = gid & 1; }
    else { int j = gid - 1024; qw = 63 - (j >> 4); h = 8 + ((j >> 1) & 7); b = j & 1; }

    const int q0 = qw * 32;
    const int kvh = h >> 1;
    const bool local = (h >= 8);
    int window = *winp;
    if (window < 0 || window > TT) window = TT;
    const int tid = threadIdx.x;
    const int w = tid >> 6;
    const int lane = tid & 63;
    const int lr = lane & 15, lc = lane >> 4;

    __shared__ ushort Ps[4][16][72];        // per-wave P^T scratch
    __shared__ float4v Ol[4][4][64];        // [wave][ct][lane] per rt phase
    __shared__ float Ll[4][16];             // per-wave row sums per rt phase

    const ushort* qbase = &Qb[(((size_t)b * NH + h) * TT + q0) * HD];
    short8 qf[2][2];
    #pragma unroll
    for (int rt = 0; rt < 2; rt++)
        #pragma unroll
        for (int xh = 0; xh < 2; xh++)
            qf[rt][xh] = *(const short8*)&qbase[(size_t)(rt * 16 + lr) * HD + xh * 32 + lc * 8];

    float4v o[2][4] = {};
    float l_[2] = {0.f, 0.f};               // lane-local partial row sums

    const ushort* Kbase = &Kb[((size_t)b * NKV + kvh) * TT * HD];
    const ushort* Vbase = &Vt[((size_t)b * NKV + kvh) * HD * TT];

    const int qlast = q0 + 31;
    int jstart = 0;
    if (local) { int js = q0 - window; if (js > 0) jstart = js & ~63; }
    const int j0first = jstart + w * 64;    // this wave's first key tile

    short8 kf[4][2];
    if (j0first <= qlast) {
        #pragma unroll
        for (int jt = 0; jt < 4; jt++) {
            const ushort* kp = &Kbase[(size_t)(j0first + jt * 16 + lr) * HD + lc * 8];
            kf[jt][0] = *(const short8*)kp;
            kf[jt][1] = *(const short8*)(kp + 32);
        }
    }

    for (int j0 = j0first; j0 <= qlast; j0 += 256) {
        short8 vf[4][2];
        #pragma unroll
        for (int ct = 0; ct < 4; ct++) {
            const ushort* vp = &Vbase[(size_t)(ct * 16 + lr) * TT + j0 + lc * 8];
            vf[ct][0] = *(const short8*)vp;
            vf[ct][1] = *(const short8*)(vp + 32);
        }
        short8 kn[4][2];
        const bool more = (j0 + 256 <= qlast);
        if (more) {
            #pragma unroll
            for (int jt = 0; jt < 4; jt++) {
                const ushort* kp = &Kbase[(size_t)(j0 + 256 + jt * 16 + lr) * HD + lc * 8];
                kn[jt][0] = *(const short8*)kp;
                kn[jt][1] = *(const short8*)(kp + 32);
            }
        }

        // S^T = K·Q^T : D[row=key][col=qrow]
        float4v st[2][4];
        #pragma unroll
        for (int jt = 0; jt < 4; jt++)
            #pragma unroll
            for (int rt = 0; rt < 2; rt++) {
                float4v z = {};
                z = __builtin_amdgcn_mfma_f32_16x16x32_bf16(kf[jt][0], qf[rt][0], z, 0, 0, 0);
                z = __builtin_amdgcn_mfma_f32_16x16x32_bf16(kf[jt][1], qf[rt][1], z, 0, 0, 0);
                st[rt][jt] = z;
            }

        const bool need_c = (j0 + 63 > q0);
        const bool need_w = local && (j0 < qlast - window);

        #pragma unroll
        for (int rt = 0; rt < 2; rt++) {
            const int qrow = q0 + rt * 16 + lr;
            float p[4][4];
            if (need_c || need_w) {
                #pragma unroll
                for (int jt = 0; jt < 4; jt++)
                    #pragma unroll
                    for (int r = 0; r < 4; r++) {
                        int key = j0 + jt * 16 + lc * 4 + r;
                        bool ok = (key <= qrow) && (!local || key >= qrow - window);
                        p[jt][r] = ok ? __expf(st[rt][jt][r] * 0.125f) : 0.f;
                    }
            } else {
                #pragma unroll
                for (int jt = 0; jt < 4; jt++)
                    #pragma unroll
                    for (int r = 0; r < 4; r++)
                        p[jt][r] = __expf(st[rt][jt][r] * 0.125f);
            }
            // lane-local tree sum (no shuffles; reduced once at the end)
            float s0 = (p[0][0] + p[0][1]) + (p[0][2] + p[0][3]);
            float s1 = (p[1][0] + p[1][1]) + (p[1][2] + p[1][3]);
            float s2 = (p[2][0] + p[2][1]) + (p[2][2] + p[2][3]);
            float s3 = (p[3][0] + p[3][1]) + (p[3][2] + p[3][3]);
            l_[rt] += (s0 + s1) + (s2 + s3);

            // P^T -> LDS (packed b64 writes): Ps[qrow][key]
            #pragma unroll
            for (int jt = 0; jt < 4; jt++) {
                ushort4 u;
                u.x = f2bf(p[jt][0]); u.y = f2bf(p[jt][1]);
                u.z = f2bf(p[jt][2]); u.w = f2bf(p[jt][3]);
                *(ushort4*)&Ps[w][lr][jt * 16 + lc * 4] = u;
            }
            short8 pb0 = *(const short8*)&Ps[w][lr][lc * 8];
            short8 pb1 = *(const short8*)&Ps[w][lr][32 + lc * 8];
            #pragma unroll
            for (int ct = 0; ct < 4; ct++) {
                o[rt][ct] = __builtin_amdgcn_mfma_f32_16x16x32_bf16(vf[ct][0], pb0, o[rt][ct], 0, 0, 0);
                o[rt][ct] = __builtin_amdgcn_mfma_f32_16x16x32_bf16(vf[ct][1], pb1, o[rt][ct], 0, 0, 0);
            }
        }

        if (more) {
            #pragma unroll
            for (int jt = 0; jt < 4; jt++) {
                kf[jt][0] = kn[jt][0];
                kf[jt][1] = kn[jt][1];
            }
        }
    }

    // reduce l across the 4 lc groups (once per rt, not per tile)
    #pragma unroll
    for (int rt = 0; rt < 2; rt++) {
        l_[rt] += __shfl_xor(l_[rt], 16);
        l_[rt] += __shfl_xor(l_[rt], 32);
    }

    // ---- merge across the 4 key-stripe waves: exact sums ----
    #pragma unroll
    for (int rt = 0; rt < 2; rt++) {
        #pragma unroll
        for (int ct = 0; ct < 4; ct++) Ol[w][ct][lane] = o[rt][ct];
        if (lc == 0) Ll[w][lr] = l_[rt];
        __syncthreads();

        {
            const int ct = w;
            float ltot = (Ll[0][lr] + Ll[1][lr]) + (Ll[2][lr] + Ll[3][lr]);
            float inv = 1.f / fmaxf(ltot, 1e-20f);
            float4v a0 = Ol[0][ct][lane], a1 = Ol[1][ct][lane];
            float4v a2 = Ol[2][ct][lane], a3 = Ol[3][ct][lane];
            int qrow = q0 + rt * 16 + lr;
            ushort4 u;
            u.x = f2bf(((a0[0] + a1[0]) + (a2[0] + a3[0])) * inv);
            u.y = f2bf(((a0[1] + a1[1]) + (a2[1] + a3[1])) * inv);
            u.z = f2bf(((a0[2] + a1[2]) + (a2[2] + a3[2])) * inv);
            u.w = f2bf(((a0[3] + a1[3]) + (a2[3] + a3[3])) * inv);
            *(ushort4*)&Yb[((size_t)b * TT + qrow) * CC + h * 64 + ct * 16 + lc * 4] = u;
        }
        if (rt == 0) __syncthreads();
    }
}

// ---------------------------------------------------------------------------
extern "C" void kernel_launch(void* const* d_in, const int* in_sizes, int n_in,
                              void* d_out, int out_size, void* d_ws, size_t ws_size,
                              hipStream_t stream) {
    (void)in_sizes; (void)n_in; (void)out_size; (void)ws_size;
    const float* x     = (const float*)d_in[0];
    const float* ve    = (const float*)d_in[1];
    const float* cosb  = (const float*)d_in[2];
    const float* sinb  = (const float*)d_in[3];
    const float* Wq    = (const float*)d_in[4];
    const float* Wk    = (const float*)d_in[5];
    const float* Wv    = (const float*)d_in[6];
    const float* Wproj = (const float*)d_in[7];
    const float* Wgate = (const float*)d_in[8];
    const int*   winp  = (const int*)d_in[9];
    float* out = (float*)d_out;

    char* ws = (char*)d_ws;
    float*  qkv   = (float*)ws;                      // 32 MiB (dead after qkv_post)
    ushort* Yb    = (ushort*)ws;                     // 8 MiB, overlays qkv
    ushort* xb    = (ushort*)(ws + 33554432);        // 8 MiB
    ushort* WqkvT = (ushort*)(ws + 41943040);        // 4 MiB: [2048][1024] = W^T
    ushort* WpT   = (ushort*)(ws + 46137344);        // 2 MiB: [1024][1024] = Wproj^T
    ushort* Qb    = (ushort*)(ws + 48234496);        // 8 MiB
    ushort* Kb    = (ushort*)(ws + 56623104);        // 4 MiB
    ushort* Vtb   = (ushort*)(ws + 60817408);        // 4 MiB (B,NKV,HD,T)

    dim3 blk(256);
    conv_kernel<<<dim3(4096), blk, 0, stream>>>(x, xb, BB * TT * CC);
    transpose_conv_kernel<<<dim3(16, 16), blk, 0, stream>>>(Wq, WqkvT, 1024, 1024);
    transpose_conv_kernel<<<dim3(16, 8), blk, 0, stream>>>(Wk, WqkvT + (size_t)1024 * 1024, 1024, 512);
    transpose_conv_kernel<<<dim3(16, 8), blk, 0, stream>>>(Wv, WqkvT + (size_t)1536 * 1024, 1024, 512);
    transpose_conv_kernel<<<dim3(16, 16), blk, 0, stream>>>(Wproj, WpT, 1024, 1024);
    gemm_bt_kernel<<<dim3(32, 16), blk, 0, stream>>>(xb, WqkvT, qkv, 4096, 2048, 1024, 2048);
    qkv_post_kernel<<<dim3(BB * TT), blk, 0, stream>>>(qkv, x, ve, cosb, sinb, Wgate, Qb, Kb, Vtb);
    // attention: 2048 blocks x 4 key-stripe waves, heavy-first
    attn_kernel<<<dim3(2048), blk, 0, stream>>>(Qb, Kb, Vtb, Yb, winp);
    gemm_bt_kernel<<<dim3(32, 8), blk, 0, stream>>>(Yb, WpT, out, 4096, 1024, 1024, 1024);
}

// Round 8
// 222.158 us; speedup vs baseline: 1.7528x; 1.1008x over previous
//
#include <hip/hip_runtime.h>
#include <hip/hip_bf16.h>

// Problem constants (B=2, T=2048, C=1024, NH=16, NKV=8, HD=64, Q_PER_KV=2)
#define BB 2
#define TT 2048
#define CC 1024
#define NH 16
#define NKV 8
#define HD 64

typedef __attribute__((ext_vector_type(8))) short short8;   // 8 bf16 (MFMA A/B frag)
typedef __attribute__((ext_vector_type(4))) float float4v;  // MFMA C/D frag

__device__ __forceinline__ ushort f2bf(float f) {
    __hip_bfloat16 h = __float2bfloat16(f);
    union { __hip_bfloat16 h; ushort u; } v; v.h = h; return v.u;
}

// async global->LDS, 16B per lane; lptr must be wave-uniform, HW adds lane*16
__device__ __forceinline__ void gload16(const ushort* g, ushort* l) {
    __builtin_amdgcn_global_load_lds(
        (const __attribute__((address_space(1))) unsigned int*)g,
        (__attribute__((address_space(3))) unsigned int*)l, 16, 0, 0);
}

// ---------------------------------------------------------------------------
// Fused prep: x f32->bf16 conv (blocks 0..4095) + weight transposes
// (f32 [K][N] -> bf16 [N][K], 64x64 LDS tiles). One launch instead of 5.
// ---------------------------------------------------------------------------
__device__ __forceinline__ void transpose_tile(
    const float* __restrict__ src, ushort* __restrict__ dst,
    int Kd, int Nd, int kt, int nt, float* tile /*[64][65]*/)
{
    const int tid = threadIdx.x;
    {
        int r = tid >> 2, c = (tid & 3) * 16;
        #pragma unroll
        for (int i = 0; i < 4; i++) {
            float4 v = *(const float4*)&src[(size_t)(kt + r) * Nd + nt + c + i * 4];
            tile[r * 65 + c + i * 4 + 0] = v.x;
            tile[r * 65 + c + i * 4 + 1] = v.y;
            tile[r * 65 + c + i * 4 + 2] = v.z;
            tile[r * 65 + c + i * 4 + 3] = v.w;
        }
    }
    __syncthreads();
    {
        int n = tid >> 2, k = (tid & 3) * 16;
        #pragma unroll
        for (int i = 0; i < 2; i++) {
            ushort u[8];
            #pragma unroll
            for (int j = 0; j < 8; j++) u[j] = f2bf(tile[(k + i * 8 + j) * 65 + n]);
            *(uint4*)&dst[(size_t)(nt + n) * Kd + kt + k + i * 8] = *(uint4*)u;
        }
    }
}

__global__ __launch_bounds__(256) void prep_kernel(
    const float* __restrict__ x, ushort* __restrict__ xb,
    const float* __restrict__ Wq, const float* __restrict__ Wk,
    const float* __restrict__ Wv, const float* __restrict__ Wproj,
    ushort* __restrict__ WqkvT, ushort* __restrict__ WpT)
{
    __shared__ float tile[64 * 65];
    const int bid = blockIdx.x;
    if (bid < 4096) {              // x conversion: 4M f32, 4/thread
        int i = (bid * 256 + threadIdx.x) * 4;
        float4 v = *(const float4*)&x[i];
        xb[i + 0] = f2bf(v.x);
        xb[i + 1] = f2bf(v.y);
        xb[i + 2] = f2bf(v.z);
        xb[i + 3] = f2bf(v.w);
        return;
    }
    int t = bid - 4096;
    if (t < 256) {                 // Wq: 1024x1024, 16x16 tiles
        transpose_tile(Wq, WqkvT, 1024, 1024, (t >> 4) * 64, (t & 15) * 64, tile);
    } else if (t < 384) {          // Wk: 1024x512
        t -= 256;
        transpose_tile(Wk, WqkvT + (size_t)1024 * 1024, 1024, 512, (t >> 3) * 64, (t & 7) * 64, tile);
    } else if (t < 512) {          // Wv: 1024x512
        t -= 384;
        transpose_tile(Wv, WqkvT + (size_t)1536 * 1024, 1024, 512, (t >> 3) * 64, (t & 7) * 64, tile);
    } else {                       // Wproj: 1024x1024
        t -= 512;
        transpose_tile(Wproj, WpT, 1024, 1024, (t >> 4) * 64, (t & 15) * 64, tile);
    }
}

// ---------------------------------------------------------------------------
// bf16 GEMM (m97 structure): C = A @ Bt^T. A[M][K], Bt[N][K] row-major bf16,
// C f32. Tile BMx128, BK=32, 4 waves; global_load_lds staging, no conflicts.
// ---------------------------------------------------------------------------
template<int BM>
__global__ __launch_bounds__(256) void gemm_bt_kernel(
    const ushort* __restrict__ A, const ushort* __restrict__ Bt,
    float* __restrict__ Cp, int M, int N, int K, int ldc)
{
    constexpr int RT = BM / 32;
    __shared__ ushort As[BM][32];    // [m][k] — unpadded (global_load_lds order)
    __shared__ ushort Bs[128][32];   // [n][k]

    const int m0 = blockIdx.x * BM;
    const int n0 = blockIdx.y * 128;
    const int tid = threadIdx.x;
    const int lane = tid & 63;
    const int w = tid >> 6;
    const int lr = lane & 15, lc = lane >> 4;
    const int wm = (w >> 1) * (BM / 2), wn = (w & 1) * 64;

    float4v acc[RT][4] = {};

    for (int k0 = 0; k0 < K; k0 += 32) {
        #pragma unroll
        for (int s = 0; s < BM / 64; s++) {
            int rb = w * (BM / 4) + s * 16;
            gload16(&A[(size_t)(m0 + rb + (lane >> 2)) * K + k0 + (lane & 3) * 8], &As[rb][0]);
        }
        #pragma unroll
        for (int s = 0; s < 2; s++) {
            int rb = w * 32 + s * 16;
            gload16(&Bt[(size_t)(n0 + rb + (lane >> 2)) * K + k0 + (lane & 3) * 8], &Bs[rb][0]);
        }
        __syncthreads();

        short8 af[RT], bf[4];
        #pragma unroll
        for (int t = 0; t < RT; t++)
            af[t] = *(const short8*)&As[wm + t * 16 + lr][lc * 8];
        #pragma unroll
        for (int t = 0; t < 4; t++)
            bf[t] = *(const short8*)&Bs[wn + t * 16 + lr][lc * 8];
        #pragma unroll
        for (int rt = 0; rt < RT; rt++)
            #pragma unroll
            for (int ct = 0; ct < 4; ct++)
                acc[rt][ct] = __builtin_amdgcn_mfma_f32_16x16x32_bf16(af[rt], bf[ct], acc[rt][ct], 0, 0, 0);
        __syncthreads();
    }

    #pragma unroll
    for (int rt = 0; rt < RT; rt++)
        #pragma unroll
        for (int ct = 0; ct < 4; ct++)
            #pragma unroll
            for (int r = 0; r < 4; r++) {
                int row = m0 + wm + rt * 16 + lc * 4 + r;
                int col = n0 + wn + ct * 16 + lr;
                Cp[(size_t)row * ldc + col] = acc[rt][ct][r];
            }
}

// ---------------------------------------------------------------------------
// Per-(b,t): gate + ve-add, RoPE + RMSNorm. qkv row = [q(1024)|k(512)|v(512)] f32.
// Writes Q (B,NH,T,HD), K (B,NKV,T,HD), V natural (B,NKV,T,HD) — all coalesced.
// ---------------------------------------------------------------------------
__global__ __launch_bounds__(256) void qkv_post_kernel(
    const float* __restrict__ qkv, const float* __restrict__ x,
    const float* __restrict__ ve, const float* __restrict__ cosb,
    const float* __restrict__ sinb, const float* __restrict__ wgate,
    ushort* __restrict__ Qb, ushort* __restrict__ Kb, ushort* __restrict__ Vn)
{
    const int bt = blockIdx.x;
    const int b = bt >> 11, t = bt & 2047;
    const int tid = threadIdx.x;
    const int lane = tid & 63;
    const int w = tid >> 6;
    __shared__ float gateS[8];

    {
        int g = tid >> 5, i = tid & 31;
        float p = x[(size_t)bt * CC + i] * wgate[i * 8 + g];
        #pragma unroll
        for (int off = 16; off; off >>= 1) p += __shfl_down(p, off, 32);
        if (i == 0) gateS[g] = 2.f / (1.f + __expf(-p));
    }
    __syncthreads();

    const float c = cosb[t * 32 + (lane & 31)];
    const float s = sinb[t * 32 + (lane & 31)];
    for (int hh = w; hh < 24; hh += 4) {
        const float* z = &qkv[(size_t)bt * 2048 + hh * 64];
        float v = z[lane];
        float other = __shfl_xor(v, 32);
        float x1 = (lane < 32) ? v : other;
        float x2 = (lane < 32) ? other : v;
        float val = (lane < 32) ? (x1 * c + x2 * s) : (-x1 * s + x2 * c);
        float ss = val * val;
        #pragma unroll
        for (int off = 32; off; off >>= 1) ss += __shfl_xor(ss, off);
        float scale = rsqrtf(ss * (1.f / 64.f) + 1.1920929e-07f);
        ushort ob = f2bf(val * scale);
        if (hh < 16) Qb[(((size_t)b * NH + hh) * TT + t) * HD + lane] = ob;
        else         Kb[(((size_t)b * NKV + (hh - 16)) * TT + t) * HD + lane] = ob;
    }

    // v = v + gate*ve; natural layout (contiguous d) — coalesced
    for (int e = tid; e < NKV * HD; e += 256) {
        int kh = e >> 6, d = e & 63;
        float v = qkv[(size_t)bt * 2048 + 1536 + e] + gateS[kh] * ve[(size_t)bt * 512 + e];
        Vn[(((size_t)b * NKV + kh) * TT + t) * HD + d] = f2bf(v);
    }
}

// ---------------------------------------------------------------------------
// V natural (B,NKV,T,HD) -> V^T (B,NKV,HD,T): LDS-tiled, coalesced both ways.
// grid = (T/64, B*NKV)
// ---------------------------------------------------------------------------
__global__ __launch_bounds__(256) void v_transpose_kernel(
    const ushort* __restrict__ Vn, ushort* __restrict__ Vt)
{
    __shared__ ushort tile[64][72];
    const int t0 = blockIdx.x * 64;
    const int bh = blockIdx.y;
    const ushort* src = &Vn[(size_t)bh * TT * HD + (size_t)t0 * HD];
    ushort* dst = &Vt[(size_t)bh * HD * TT + t0];
    const int tid = threadIdx.x;
    {
        int r = tid >> 2, c = (tid & 3) * 16;   // r = t offset, c = d offset
        #pragma unroll
        for (int i = 0; i < 2; i++)
            *(uint4*)&tile[r][c + i * 8] = *(const uint4*)&src[(size_t)r * HD + c + i * 8];
    }
    __syncthreads();
    {
        int d = tid >> 2, c = (tid & 3) * 16;   // d row out, c = t offset
        #pragma unroll
        for (int i = 0; i < 2; i++) {
            ushort u[8];
            #pragma unroll
            for (int j = 0; j < 8; j++) u[j] = tile[c + i * 8 + j][d];
            *(uint4*)&dst[(size_t)d * TT + c + i * 8] = *(uint4*)u;
        }
    }
}

// ---------------------------------------------------------------------------
// Split-KV flash attention, unnormalized exp (q,k RMS-normed -> |s|<=8, f32
// safe). 4 waves stripe key tiles; exact-sum merge. (unchanged from round 7)
// ---------------------------------------------------------------------------
__global__ __launch_bounds__(256) void attn_kernel(
    const ushort* __restrict__ Qb, const ushort* __restrict__ Kb,
    const ushort* __restrict__ Vt, ushort* __restrict__ Yb,
    const int* __restrict__ winp)
{
    const int gid = blockIdx.x;
    int b, h, qw;
    if (gid < 1024) { qw = 63 - (gid >> 4); h = (gid >> 1) & 7; b = gid & 1; }
    else { int j = gid - 1024; qw = 63 - (j >> 4); h = 8 + ((j >> 1) & 7); b = j & 1; }

    const int q0 = qw * 32;
    const int kvh = h >> 1;
    const bool local = (h >= 8);
    int window = *winp;
    if (window < 0 || window > TT) window = TT;
    const int tid = threadIdx.x;
    const int w = tid >> 6;
    const int lane = tid & 63;
    const int lr = lane & 15, lc = lane >> 4;

    __shared__ ushort Ps[4][16][72];
    __shared__ float4v Ol[4][4][64];
    __shared__ float Ll[4][16];

    const ushort* qbase = &Qb[(((size_t)b * NH + h) * TT + q0) * HD];
    short8 qf[2][2];
    #pragma unroll
    for (int rt = 0; rt < 2; rt++)
        #pragma unroll
        for (int xh = 0; xh < 2; xh++)
            qf[rt][xh] = *(const short8*)&qbase[(size_t)(rt * 16 + lr) * HD + xh * 32 + lc * 8];

    float4v o[2][4] = {};
    float l_[2] = {0.f, 0.f};

    const ushort* Kbase = &Kb[((size_t)b * NKV + kvh) * TT * HD];
    const ushort* Vbase = &Vt[((size_t)b * NKV + kvh) * HD * TT];

    const int qlast = q0 + 31;
    int jstart = 0;
    if (local) { int js = q0 - window; if (js > 0) jstart = js & ~63; }
    const int j0first = jstart + w * 64;

    short8 kf[4][2];
    if (j0first <= qlast) {
        #pragma unroll
        for (int jt = 0; jt < 4; jt++) {
            const ushort* kp = &Kbase[(size_t)(j0first + jt * 16 + lr) * HD + lc * 8];
            kf[jt][0] = *(const short8*)kp;
            kf[jt][1] = *(const short8*)(kp + 32);
        }
    }

    for (int j0 = j0first; j0 <= qlast; j0 += 256) {
        short8 vf[4][2];
        #pragma unroll
        for (int ct = 0; ct < 4; ct++) {
            const ushort* vp = &Vbase[(size_t)(ct * 16 + lr) * TT + j0 + lc * 8];
            vf[ct][0] = *(const short8*)vp;
            vf[ct][1] = *(const short8*)(vp + 32);
        }
        short8 kn[4][2];
        const bool more = (j0 + 256 <= qlast);
        if (more) {
            #pragma unroll
            for (int jt = 0; jt < 4; jt++) {
                const ushort* kp = &Kbase[(size_t)(j0 + 256 + jt * 16 + lr) * HD + lc * 8];
                kn[jt][0] = *(const short8*)kp;
                kn[jt][1] = *(const short8*)(kp + 32);
            }
        }

        float4v st[2][4];
        #pragma unroll
        for (int jt = 0; jt < 4; jt++)
            #pragma unroll
            for (int rt = 0; rt < 2; rt++) {
                float4v z = {};
                z = __builtin_amdgcn_mfma_f32_16x16x32_bf16(kf[jt][0], qf[rt][0], z, 0, 0, 0);
                z = __builtin_amdgcn_mfma_f32_16x16x32_bf16(kf[jt][1], qf[rt][1], z, 0, 0, 0);
                st[rt][jt] = z;
            }

        const bool need_c = (j0 + 63 > q0);
        const bool need_w = local && (j0 < qlast - window);

        #pragma unroll
        for (int rt = 0; rt < 2; rt++) {
            const int qrow = q0 + rt * 16 + lr;
            float p[4][4];
            if (need_c || need_w) {
                #pragma unroll
                for (int jt = 0; jt < 4; jt++)
                    #pragma unroll
                    for (int r = 0; r < 4; r++) {
                        int key = j0 + jt * 16 + lc * 4 + r;
                        bool ok = (key <= qrow) && (!local || key >= qrow - window);
                        p[jt][r] = ok ? __expf(st[rt][jt][r] * 0.125f) : 0.f;
                    }
            } else {
                #pragma unroll
                for (int jt = 0; jt < 4; jt++)
                    #pragma unroll
                    for (int r = 0; r < 4; r++)
                        p[jt][r] = __expf(st[rt][jt][r] * 0.125f);
            }
            float s0 = (p[0][0] + p[0][1]) + (p[0][2] + p[0][3]);
            float s1 = (p[1][0] + p[1][1]) + (p[1][2] + p[1][3]);
            float s2 = (p[2][0] + p[2][1]) + (p[2][2] + p[2][3]);
            float s3 = (p[3][0] + p[3][1]) + (p[3][2] + p[3][3]);
            l_[rt] += (s0 + s1) + (s2 + s3);

            #pragma unroll
            for (int jt = 0; jt < 4; jt++) {
                ushort4 u;
                u.x = f2bf(p[jt][0]); u.y = f2bf(p[jt][1]);
                u.z = f2bf(p[jt][2]); u.w = f2bf(p[jt][3]);
                *(ushort4*)&Ps[w][lr][jt * 16 + lc * 4] = u;
            }
            short8 pb0 = *(const short8*)&Ps[w][lr][lc * 8];
            short8 pb1 = *(const short8*)&Ps[w][lr][32 + lc * 8];
            #pragma unroll
            for (int ct = 0; ct < 4; ct++) {
                o[rt][ct] = __builtin_amdgcn_mfma_f32_16x16x32_bf16(vf[ct][0], pb0, o[rt][ct], 0, 0, 0);
                o[rt][ct] = __builtin_amdgcn_mfma_f32_16x16x32_bf16(vf[ct][1], pb1, o[rt][ct], 0, 0, 0);
            }
        }

        if (more) {
            #pragma unroll
            for (int jt = 0; jt < 4; jt++) {
                kf[jt][0] = kn[jt][0];
                kf[jt][1] = kn[jt][1];
            }
        }
    }

    #pragma unroll
    for (int rt = 0; rt < 2; rt++) {
        l_[rt] += __shfl_xor(l_[rt], 16);
        l_[rt] += __shfl_xor(l_[rt], 32);
    }

    #pragma unroll
    for (int rt = 0; rt < 2; rt++) {
        #pragma unroll
        for (int ct = 0; ct < 4; ct++) Ol[w][ct][lane] = o[rt][ct];
        if (lc == 0) Ll[w][lr] = l_[rt];
        __syncthreads();

        {
            const int ct = w;
            float ltot = (Ll[0][lr] + Ll[1][lr]) + (Ll[2][lr] + Ll[3][lr]);
            float inv = 1.f / fmaxf(ltot, 1e-20f);
            float4v a0 = Ol[0][ct][lane], a1 = Ol[1][ct][lane];
            float4v a2 = Ol[2][ct][lane], a3 = Ol[3][ct][lane];
            int qrow = q0 + rt * 16 + lr;
            ushort4 u;
            u.x = f2bf(((a0[0] + a1[0]) + (a2[0] + a3[0])) * inv);
            u.y = f2bf(((a0[1] + a1[1]) + (a2[1] + a3[1])) * inv);
            u.z = f2bf(((a0[2] + a1[2]) + (a2[2] + a3[2])) * inv);
            u.w = f2bf(((a0[3] + a1[3]) + (a2[3] + a3[3])) * inv);
            *(ushort4*)&Yb[((size_t)b * TT + qrow) * CC + h * 64 + ct * 16 + lc * 4] = u;
        }
        if (rt == 0) __syncthreads();
    }
}

// ---------------------------------------------------------------------------
extern "C" void kernel_launch(void* const* d_in, const int* in_sizes, int n_in,
                              void* d_out, int out_size, void* d_ws, size_t ws_size,
                              hipStream_t stream) {
    (void)in_sizes; (void)n_in; (void)out_size; (void)ws_size;
    const float* x     = (const float*)d_in[0];
    const float* ve    = (const float*)d_in[1];
    const float* cosb  = (const float*)d_in[2];
    const float* sinb  = (const float*)d_in[3];
    const float* Wq    = (const float*)d_in[4];
    const float* Wk    = (const float*)d_in[5];
    const float* Wv    = (const float*)d_in[6];
    const float* Wproj = (const float*)d_in[7];
    const float* Wgate = (const float*)d_in[8];
    const int*   winp  = (const int*)d_in[9];
    float* out = (float*)d_out;

    char* ws = (char*)d_ws;
    float*  qkv   = (float*)ws;                      // 32 MiB (dead after qkv_post)
    ushort* Yb    = (ushort*)ws;                     // 8 MiB, overlays qkv
    ushort* xb    = (ushort*)(ws + 33554432);        // 8 MiB (dead after QKV GEMM)
    ushort* Vnb   = (ushort*)(ws + 33554432);        // 4 MiB natural V, overlays xb
    ushort* WqkvT = (ushort*)(ws + 41943040);        // 4 MiB: [2048][1024] = W^T
    ushort* WpT   = (ushort*)(ws + 46137344);        // 2 MiB: [1024][1024] = Wproj^T
    ushort* Qb    = (ushort*)(ws + 48234496);        // 8 MiB
    ushort* Kb    = (ushort*)(ws + 56623104);        // 4 MiB
    ushort* Vtb   = (ushort*)(ws + 60817408);        // 4 MiB (B,NKV,HD,T)

    dim3 blk(256);
    // fused prep: x conv (4096 blocks) + 4 weight transposes (768 blocks)
    prep_kernel<<<dim3(4864), blk, 0, stream>>>(x, xb, Wq, Wk, Wv, Wproj, WqkvT, WpT);
    // fused QKV projection (f32 out, row = [q|k|v])
    gemm_bt_kernel<128><<<dim3(32, 16), blk, 0, stream>>>(xb, WqkvT, qkv, 4096, 2048, 1024, 2048);
    // gate/ve/rope/rmsnorm; V written natural (coalesced) into dead xb region
    qkv_post_kernel<<<dim3(BB * TT), blk, 0, stream>>>(qkv, x, ve, cosb, sinb, Wgate, Qb, Kb, Vnb);
    // V natural -> V^T, LDS-tiled coalesced
    v_transpose_kernel<<<dim3(TT / 64, BB * NKV), blk, 0, stream>>>(Vnb, Vtb);
    // attention: 2048 blocks x 4 key-stripe waves, heavy-first
    attn_kernel<<<dim3(2048), blk, 0, stream>>>(Qb, Kb, Vtb, Yb, winp);
    // output projection -> f32 d_out (BM=64: 512 blocks, 2/CU)
    gemm_bt_kernel<64><<<dim3(64, 8), blk, 0, stream>>>(Yb, WpT, out, 4096, 1024, 1024, 1024);
}